// Round 6
// baseline (3742.165 us; speedup 1.0000x reference)
//
#include <hip/hip_runtime.h>

typedef unsigned short u16;
typedef __bf16 bf16;
typedef __attribute__((ext_vector_type(8))) __bf16 bf16x8;
typedef __attribute__((ext_vector_type(4))) float f32x4;
typedef __attribute__((ext_vector_type(8))) unsigned short u16x8;

__device__ __forceinline__ float bf2f(u16 h) {
  return __uint_as_float(((unsigned int)h) << 16);
}
__device__ __forceinline__ u16 f2bf(float f) {
  unsigned int u = __float_as_uint(f);
  return (u16)((u + 0x7fffu + ((u >> 16) & 1u)) >> 16);
}
// dual-dtype scalar read -> bf16 bits
__device__ __forceinline__ u16 ld_cv(const void* p, size_t i, int f32) {
  return f32 ? f2bf(((const float*)p)[i]) : ((const u16*)p)[i];
}
// async global->LDS, 16B per lane; LDS dest = wave-uniform base + lane*16.
__device__ __forceinline__ void async16(const u16* g, u16* l) {
  __builtin_amdgcn_global_load_lds(
      (const __attribute__((address_space(1))) unsigned int*)g,
      (__attribute__((address_space(3))) unsigned int*)l, 16, 0, 0);
}
// pack two fp32 -> two bf16 (round-to-nearest-ish via +0x8000, then v_perm)
__device__ __forceinline__ unsigned pk_bf16(float hi, float lo) {
  return __builtin_amdgcn_perm(__float_as_uint(hi) + 0x8000u,
                               __float_as_uint(lo) + 0x8000u, 0x07060302u);
}

// ---- dtype sniffer: even u16s of fp32 data are mantissa garbage ----------
__global__ void sniff_kernel(const u16* __restrict__ x, int* __restrict__ flag) {
  const int tid = threadIdx.x;
  int me = 0;
#pragma unroll
  for (int j = 0; j < 4; j++) {
    const u16 v = x[(tid * 4 + j) * 2];
    const int e = (v >> 7) & 0xFF;
    me = me > e ? me : e;
  }
#pragma unroll
  for (int off = 32; off > 0; off >>= 1) {
    const int o = __shfl_down(me, off);
    me = me > o ? me : o;
  }
  __shared__ int sm[4];
  if ((tid & 63) == 0) sm[tid >> 6] = me;
  __syncthreads();
  if (tid == 0) {
    int a = sm[0] > sm[1] ? sm[0] : sm[1];
    int b = sm[2] > sm[3] ? sm[2] : sm[3];
    *flag = ((a > b ? a : b) >= 140) ? 1 : 0;
  }
}

// ---- canonicalize x to bf16 (4M elems, 8 elems/thread) -------------------
__global__ void conv_x(const void* __restrict__ src, u16* __restrict__ dst,
                       const int* __restrict__ flag) {
  const size_t i = ((size_t)blockIdx.x * 256 + threadIdx.x) * 8;
  if (*flag) {
    const float4* f = (const float4*)((const float*)src + i);
    const float4 a = f[0], b = f[1];
    u16x8 o;
    o[0] = f2bf(a.x); o[1] = f2bf(a.y); o[2] = f2bf(a.z); o[3] = f2bf(a.w);
    o[4] = f2bf(b.x); o[5] = f2bf(b.y); o[6] = f2bf(b.z); o[7] = f2bf(b.w);
    *(u16x8*)(dst + i) = o;
  } else {
    *(u16x8*)(dst + i) = *(const u16x8*)((const u16*)src + i);
  }
}

// ---- canonicalize the 6 small vectors (b1|b2|g1|be1|g2|be2 = 9216 elems) --
__global__ void conv_small(const void* b1, const void* b2, const void* g1,
                           const void* be1, const void* g2, const void* be2,
                           u16* __restrict__ dst, const int* __restrict__ flag) {
  const int e = blockIdx.x * 256 + threadIdx.x;
  if (e >= 9216) return;
  const int f = *flag;
  if (e < 4096) {
    dst[e] = ld_cv(b1, e, f);
  } else {
    const int k = (e - 4096) >> 10, off = (e - 4096) & 1023;
    const void* p = (k == 0) ? b2 : (k == 1) ? g1 : (k == 2) ? be1
                    : (k == 3) ? g2 : be2;
    dst[e] = ld_cv(p, off, f);
  }
}

// ---------------- GEMM: C[m][n] = sum_k A[m][k] * BT[n][k] ----------------
template <int EPI>
__launch_bounds__(256)
__global__ void gemm_bt(const u16* __restrict__ A, const u16* __restrict__ B,
                        int K, int N,
                        const u16* __restrict__ bias, const u16* __restrict__ res,
                        void* __restrict__ out,
                        u16* __restrict__ Qo, u16* __restrict__ Ko, u16* __restrict__ Vo,
                        const int* __restrict__ flag) {
  __shared__ __align__(16) u16 As[128 * 32];
  __shared__ __align__(16) u16 Bs[128 * 32];
  const int tid = threadIdx.x;
  const int m0 = blockIdx.y * 128;
  const int n0 = blockIdx.x * 128;
  const int wave = tid >> 6, lane = tid & 63;
  const int wm = (wave >> 1) * 64, wn = (wave & 1) * 64;
  const int lm = lane & 15, lq = lane >> 4;
  const int of32 = (EPI == 2) ? *flag : 0;

  const f32x4 zero = {0.f, 0.f, 0.f, 0.f};
  f32x4 acc[4][4];
#pragma unroll
  for (int i = 0; i < 4; i++)
#pragma unroll
    for (int j = 0; j < 4; j++) acc[i][j] = zero;

  const int ar = tid >> 2;
  const int ac = (tid & 3) * 8;
  const u16* Ag = A + (size_t)(m0 + ar) * K + ac;
  const u16* Bg = B + (size_t)(n0 + ar) * K + ac;
  u16* AsP = &As[tid * 8];
  u16* BsP = &Bs[tid * 8];
  const size_t K64 = (size_t)64 * K;

  for (int k0 = 0; k0 < K; k0 += 32) {
    async16(Ag + k0, AsP);
    async16(Ag + k0 + K64, AsP + 2048);
    async16(Bg + k0, BsP);
    async16(Bg + k0 + K64, BsP + 2048);
    __syncthreads();  // drains vmcnt(0): LDS tile ready
    bf16x8 a[4], b[4];
#pragma unroll
    for (int i = 0; i < 4; i++)
      a[i] = *(const bf16x8*)&As[(wm + i * 16 + lm) * 32 + lq * 8];
#pragma unroll
    for (int i = 0; i < 4; i++)
      b[i] = *(const bf16x8*)&Bs[(wn + i * 16 + lm) * 32 + lq * 8];
#pragma unroll
    for (int i = 0; i < 4; i++)
#pragma unroll
      for (int j = 0; j < 4; j++)
        acc[i][j] = __builtin_amdgcn_mfma_f32_16x16x32_bf16(a[i], b[j], acc[i][j], 0, 0, 0);
    __syncthreads();
  }

#pragma unroll
  for (int i = 0; i < 4; i++) {
#pragma unroll
    for (int r = 0; r < 4; r++) {
      const int row = m0 + wm + i * 16 + lq * 4 + r;
#pragma unroll
      for (int j = 0; j < 4; j++) {
        const int col = n0 + wn + j * 16 + lm;
        const float c = acc[i][j][r];
        if (EPI == 0) {
          const int bb = row >> 11, t = row & 2047;
          const int w = col >> 10, nn = col & 1023;
          const int hh = nn >> 6, e = nn & 63;
          u16* dst = (w == 0) ? Qo : ((w == 1) ? Ko : Vo);
          dst[(((size_t)(bb * 16 + hh)) * 2048 + t) * 64 + e] = f2bf(c);
        } else if (EPI == 1) {
          const float v = c + bf2f(bias[col]);
          ((u16*)out)[(size_t)row * N + col] = f2bf(v > 0.f ? v : 0.f);
        } else {
          const float v = c + bf2f(bias[col]) + bf2f(res[(size_t)row * N + col]);
          if (of32)
            ((float*)out)[(size_t)row * N + col] = v;
          else
            ((u16*)out)[(size_t)row * N + col] = f2bf(v);
        }
      }
    }
  }
}

// ---------------- MFMA flash attention v4: LDS-free, register-pipelined ----
// Wave owns 32 q rows. S^T = K(A-frag) x Q(B-frag): C-layout col=q(lm),
// row=key(quad*4+r). Lane's p-values ARE a B-operand fragment for PV under
// key-permutation kappa = quad*8 + hh*4 + r; Vt A-operand loads the matching
// keys as two contiguous bf16x4 from Vt[e][t]. No LDS, no barriers. l is a
// per-lane column scalar, reduced with 2 shfl_xor at the end. K/V fragments
// double-buffered in registers (prefetch next tile before compute).
__launch_bounds__(128)
__global__ void attn_mfma(const u16* __restrict__ Q, const u16* __restrict__ K,
                          const u16* __restrict__ Vt, const u16* __restrict__ x,
                          u16* __restrict__ x2) {
  const int tid = threadIdx.x;
  const int wave = tid >> 6, lane = tid & 63;
  const int lm = lane & 15, quad = lane >> 4;
  const int gw = blockIdx.x * 2 + wave;
  const int bh = gw >> 6;
  const int qb = 63 - (gw & 63);  // longest-first
  const int qw0 = qb * 32;
  const int b = bh >> 4, h = bh & 15;

  // Q fragments (B-operand): lane holds Q[qw0+s*16+lm][quad*8..+7] (+32)
  bf16x8 qf[2][2];
#pragma unroll
  for (int s = 0; s < 2; s++) {
    const u16* Qp = Q + ((size_t)bh * 2048 + qw0 + s * 16 + lm) * 64 + quad * 8;
    qf[s][0] = *(const bf16x8*)Qp;
    qf[s][1] = *(const bf16x8*)(Qp + 32);
  }
  const f32x4 zero = {0.f, 0.f, 0.f, 0.f};
  f32x4 ot[2][4];
#pragma unroll
  for (int s = 0; s < 2; s++)
#pragma unroll
    for (int j = 0; j < 4; j++) ot[s][j] = zero;
  float l[2] = {0.f, 0.f};

  const u16* Kbh = K + (size_t)bh * 131072;
  const u16* Vbh = Vt + (size_t)bh * 131072;
  const int nt = qb + 1;

  union V8 { bf16x8 v; struct { unsigned long long lo, hi; } q; };
  bf16x8 kf[2][2][2];
  V8 vf[2][4];

  auto loadKV = [&](int ks, bf16x8 (&kfd)[2][2], V8 (&vfd)[4]) {
#pragma unroll
    for (int hh = 0; hh < 2; hh++) {
      const u16* Kp = Kbh + (size_t)(ks + hh * 16 + lm) * 64 + quad * 8;
      kfd[hh][0] = *(const bf16x8*)Kp;
      kfd[hh][1] = *(const bf16x8*)(Kp + 32);
    }
#pragma unroll
    for (int j = 0; j < 4; j++) {
      const u16* Vp = Vbh + (size_t)(j * 16 + lm) * 2048 + ks + quad * 4;
      vfd[j].q.lo = *(const unsigned long long*)Vp;
      vfd[j].q.hi = *(const unsigned long long*)(Vp + 16);
    }
  };

  loadKV(0, kf[0], vf[0]);
  int cur = 0;
  for (int tile = 0; tile < nt; tile++) {
    const int nxt = cur ^ 1;
    if (tile + 1 < nt) loadKV((tile + 1) * 32, kf[nxt], vf[nxt]);

    // S^T[key][q]
    f32x4 S[2][2];
#pragma unroll
    for (int s = 0; s < 2; s++)
#pragma unroll
      for (int hh = 0; hh < 2; hh++) {
        f32x4 a = zero;
        a = __builtin_amdgcn_mfma_f32_16x16x32_bf16(kf[cur][hh][0], qf[s][0], a, 0, 0, 0);
        a = __builtin_amdgcn_mfma_f32_16x16x32_bf16(kf[cur][hh][1], qf[s][1], a, 0, 0, 0);
        S[s][hh] = a;
      }

    const bool lastT = (tile == nt - 1);
#pragma unroll
    for (int s = 0; s < 2; s++) {
      float p[2][4];
#pragma unroll
      for (int hh = 0; hh < 2; hh++)
#pragma unroll
        for (int r = 0; r < 4; r++) {
          float v = __expf(S[s][hh][r] * 0.03125f);
          if (lastT && (hh * 16 + quad * 4 + r > s * 16 + lm)) v = 0.f;
          l[s] += v;
          p[hh][r] = v;
        }
      unsigned pk[4];
      pk[0] = pk_bf16(p[0][1], p[0][0]);
      pk[1] = pk_bf16(p[0][3], p[0][2]);
      pk[2] = pk_bf16(p[1][1], p[1][0]);
      pk[3] = pk_bf16(p[1][3], p[1][2]);
      const bf16x8 pf = *(const bf16x8*)pk;
#pragma unroll
      for (int j = 0; j < 4; j++)
        ot[s][j] = __builtin_amdgcn_mfma_f32_16x16x32_bf16(vf[cur][j].v, pf, ot[s][j], 0, 0, 0);
    }
    cur = nxt;
  }

  // l lives per-column(q=lm) per-quad; fold the 4 quads
#pragma unroll
  for (int s = 0; s < 2; s++) {
    l[s] += __shfl_xor(l[s], 16);
    l[s] += __shfl_xor(l[s], 32);
  }
  const float linv[2] = {1.f / l[0], 1.f / l[1]};

  // epilogue: x2 = x + O/l.  ot[s][j][r] = O[q=qw0+s*16+lm][e=j*16+quad*4+r]
#pragma unroll
  for (int s = 0; s < 2; s++) {
    const size_t rowbase =
        ((size_t)(b * 2048 + qw0 + s * 16 + lm)) * 1024 + h * 64;
#pragma unroll
    for (int j = 0; j < 4; j++) {
      const int e = j * 16 + quad * 4;
      const ushort4 xv = *(const ushort4*)&x[rowbase + e];
      ushort4 o4;
      o4.x = f2bf(bf2f(xv.x) + ot[s][j][0] * linv[s]);
      o4.y = f2bf(bf2f(xv.y) + ot[s][j][1] * linv[s]);
      o4.z = f2bf(bf2f(xv.z) + ot[s][j][2] * linv[s]);
      o4.w = f2bf(bf2f(xv.w) + ot[s][j][3] * linv[s]);
      *(ushort4*)&x2[rowbase + e] = o4;
    }
  }
}

// ---------------- LayerNorm (ddof=1, eps=1e-5) ----------------------------
__launch_bounds__(256)
__global__ void ln_kernel(const u16* __restrict__ x, const u16* __restrict__ gamma,
                          const u16* __restrict__ beta, u16* __restrict__ out) {
  const size_t row = blockIdx.x;
  const int tid = threadIdx.x;
  const u16* xr = x + row * 1024;
  const ushort4 u = *(const ushort4*)&xr[tid * 4];
  const float v0 = bf2f(u.x), v1 = bf2f(u.y), v2 = bf2f(u.z), v3 = bf2f(u.w);
  float s = v0 + v1 + v2 + v3;
  float sq = v0 * v0 + v1 * v1 + v2 * v2 + v3 * v3;
#pragma unroll
  for (int off = 32; off > 0; off >>= 1) {
    s += __shfl_down(s, off);
    sq += __shfl_down(sq, off);
  }
  __shared__ float ss[4], ssq[4];
  if ((tid & 63) == 0) { ss[tid >> 6] = s; ssq[tid >> 6] = sq; }
  __syncthreads();
  s = ss[0] + ss[1] + ss[2] + ss[3];
  sq = ssq[0] + ssq[1] + ssq[2] + ssq[3];
  const float mean = s * (1.f / 1024.f);
  const float var = (sq - 1024.f * mean * mean) * (1.f / 1023.f);
  const float rs = rsqrtf(var + 1e-5f);
  const ushort4 g = *(const ushort4*)&gamma[tid * 4];
  const ushort4 be = *(const ushort4*)&beta[tid * 4];
  ushort4 o;
  o.x = f2bf(bf2f(g.x) * (v0 - mean) * rs + bf2f(be.x));
  o.y = f2bf(bf2f(g.y) * (v1 - mean) * rs + bf2f(be.y));
  o.z = f2bf(bf2f(g.z) * (v2 - mean) * rs + bf2f(be.z));
  o.w = f2bf(bf2f(g.w) * (v3 - mean) * rs + bf2f(be.w));
  *(ushort4*)&out[row * 1024 + tid * 4] = o;
}

// WT[w*1024+h*64+e][d] = W_w[h][d][e]; coalesced 64x64 LDS tiles.
// grid (16 d-tiles, 48 = w*16+h)
__global__ void transpose_qkv2(const void* __restrict__ Wq, const void* __restrict__ Wk,
                               const void* __restrict__ Wv, u16* __restrict__ WT,
                               const int* __restrict__ flag) {
  __shared__ u16 tile[64][65];
  const int f = *flag;
  const int wh = blockIdx.y;
  const int w = wh >> 4, hh = wh & 15;
  const int tr = blockIdx.x * 64;  // d-range
  const void* W = (w == 0) ? Wq : ((w == 1) ? Wk : Wv);
  const size_t hbase = (size_t)hh * 65536;
  const int lx = threadIdx.x & 63, ly = threadIdx.x >> 6;
#pragma unroll
  for (int i = 0; i < 16; i++)
    tile[ly * 16 + i][lx] = ld_cv(W, hbase + (size_t)(tr + ly * 16 + i) * 64 + lx, f);
  __syncthreads();
#pragma unroll
  for (int i = 0; i < 16; i++)
    WT[((size_t)(w * 1024 + hh * 64 + ly * 16 + i)) * 1024 + tr + lx] =
        tile[lx][ly * 16 + i];
}

// dst[c*R + r] = src[r*C + c], 64x64 LDS tiles, grid (C/64, R/64), dual read
__global__ void transpose_tile(const void* __restrict__ src, u16* __restrict__ dst,
                               int R, int C, const int* __restrict__ flag) {
  __shared__ u16 tile[64][65];
  const int f = *flag;
  const int tc = blockIdx.x * 64, tr = blockIdx.y * 64;
  const int lx = threadIdx.x & 63, ly = threadIdx.x >> 6;
#pragma unroll
  for (int i = 0; i < 16; i++)
    tile[ly * 16 + i][lx] = ld_cv(src, (size_t)(tr + ly * 16 + i) * C + tc + lx, f);
  __syncthreads();
#pragma unroll
  for (int i = 0; i < 16; i++)
    dst[(size_t)(tc + ly * 16 + i) * R + tr + lx] = tile[lx][ly * 16 + i];
}

// V [bh][t][64] -> Vt [bh][e][t], batched coalesced transpose
__global__ void transpose_v(const u16* __restrict__ src, u16* __restrict__ dst) {
  __shared__ u16 tile[64][65];
  const int bh = blockIdx.y;
  const int tt = blockIdx.x * 64;
  const int lx = threadIdx.x & 63, ly = threadIdx.x >> 6;
#pragma unroll
  for (int i = 0; i < 16; i++)
    tile[ly * 16 + i][lx] = src[((size_t)bh * 2048 + tt + ly * 16 + i) * 64 + lx];
  __syncthreads();
#pragma unroll
  for (int i = 0; i < 16; i++)
    dst[((size_t)bh * 64 + ly * 16 + i) * 2048 + tt + lx] = tile[lx][ly * 16 + i];
}

extern "C" void kernel_launch(void* const* d_in, const int* in_sizes, int n_in,
                              void* d_out, int out_size, void* d_ws, size_t ws_size,
                              hipStream_t stream) {
  const void* x      = d_in[0];
  const void* Wq     = d_in[1];
  const void* Wk     = d_in[2];
  const void* Wv     = d_in[3];
  const void* W1     = d_in[4];
  const void* b1     = d_in[5];
  const void* W2     = d_in[6];
  const void* b2     = d_in[7];
  const void* gamma1 = d_in[8];
  const void* beta1  = d_in[9];
  const void* gamma2 = d_in[10];
  const void* beta2  = d_in[11];
  u16* ws = (u16*)d_ws;

  const size_t M4 = 4194304;
  u16* h   = ws;
  u16* Vtb = ws;
  u16* Qb  = ws + 1 * M4;
  u16* Kb  = ws + 2 * M4;
  u16* Vb  = ws + 3 * M4;
  u16* WTq = ws + 4 * M4;
  u16* x2  = ws + 4 * M4;
  u16* Xc  = ws + 5 * M4;
  u16* h2  = ws + 5 * M4;
  u16* W1T = ws + 6 * M4;
  u16* W2T = ws + 7 * M4;
  u16* ff1 = ws;
  u16* smallc = ws + 8 * M4;
  u16* b1c = smallc, *b2c = smallc + 4096, *g1c = smallc + 5120,
     *be1c = smallc + 6144, *g2c = smallc + 7168, *be2c = smallc + 8192;
  int* flag = (int*)(ws + 8 * M4 + 9216);

  sniff_kernel<<<1, 256, 0, stream>>>((const u16*)x, flag);
  conv_x<<<2048, 256, 0, stream>>>(x, Xc, flag);
  conv_small<<<36, 256, 0, stream>>>(b1, b2, gamma1, beta1, gamma2, beta2,
                                     smallc, flag);
  transpose_qkv2<<<dim3(16, 48), 256, 0, stream>>>(Wq, Wk, Wv, WTq, flag);
  transpose_tile<<<dim3(64, 16), 256, 0, stream>>>(W1, W1T, 1024, 4096, flag);
  transpose_tile<<<dim3(16, 64), 256, 0, stream>>>(W2, W2T, 4096, 1024, flag);
  ln_kernel<<<4096, 256, 0, stream>>>(Xc, g1c, be1c, h);
  gemm_bt<0><<<dim3(24, 32), 256, 0, stream>>>(h, WTq, 1024, 3072,
                                               nullptr, nullptr, nullptr,
                                               Qb, Kb, Vb, flag);
  transpose_v<<<dim3(32, 32), 256, 0, stream>>>(Vb, Vtb);
  attn_mfma<<<1024, 128, 0, stream>>>(Qb, Kb, Vtb, Xc, x2);
  ln_kernel<<<4096, 256, 0, stream>>>(x2, g2c, be2c, h2);
  gemm_bt<1><<<dim3(32, 32), 256, 0, stream>>>(h2, W1T, 1024, 4096,
                                               b1c, nullptr, ff1,
                                               nullptr, nullptr, nullptr, flag);
  gemm_bt<2><<<dim3(8, 32), 256, 0, stream>>>(ff1, W2T, 4096, 1024,
                                              b2c, x2, d_out,
                                              nullptr, nullptr, nullptr, flag);
}

// Round 7
// 521.535 us; speedup vs baseline: 7.1753x; 7.1753x over previous
//
#include <hip/hip_runtime.h>

typedef unsigned short u16;
typedef __bf16 bf16;
typedef __attribute__((ext_vector_type(8))) __bf16 bf16x8;
typedef __attribute__((ext_vector_type(4))) float f32x4;
typedef __attribute__((ext_vector_type(8))) unsigned short u16x8;

__device__ __forceinline__ float bf2f(u16 h) {
  return __uint_as_float(((unsigned int)h) << 16);
}
__device__ __forceinline__ u16 f2bf(float f) {
  unsigned int u = __float_as_uint(f);
  return (u16)((u + 0x7fffu + ((u >> 16) & 1u)) >> 16);
}
// dual-dtype scalar read -> bf16 bits
__device__ __forceinline__ u16 ld_cv(const void* p, size_t i, int f32) {
  return f32 ? f2bf(((const float*)p)[i]) : ((const u16*)p)[i];
}
// async global->LDS, 16B per lane; LDS dest = wave-uniform base + lane*16.
__device__ __forceinline__ void async16(const u16* g, u16* l) {
  __builtin_amdgcn_global_load_lds(
      (const __attribute__((address_space(1))) unsigned int*)g,
      (__attribute__((address_space(3))) unsigned int*)l, 16, 0, 0);
}
// pack two fp32 -> two bf16 (round-to-nearest-ish via +0x8000, then v_perm)
__device__ __forceinline__ unsigned pk_bf16(float hi, float lo) {
  return __builtin_amdgcn_perm(__float_as_uint(hi) + 0x8000u,
                               __float_as_uint(lo) + 0x8000u, 0x07060302u);
}

// ---- dtype sniffer: even u16s of fp32 data are mantissa garbage ----------
__global__ void sniff_kernel(const u16* __restrict__ x, int* __restrict__ flag) {
  const int tid = threadIdx.x;
  int me = 0;
#pragma unroll
  for (int j = 0; j < 4; j++) {
    const u16 v = x[(tid * 4 + j) * 2];
    const int e = (v >> 7) & 0xFF;
    me = me > e ? me : e;
  }
#pragma unroll
  for (int off = 32; off > 0; off >>= 1) {
    const int o = __shfl_down(me, off);
    me = me > o ? me : o;
  }
  __shared__ int sm[4];
  if ((tid & 63) == 0) sm[tid >> 6] = me;
  __syncthreads();
  if (tid == 0) {
    int a = sm[0] > sm[1] ? sm[0] : sm[1];
    int b = sm[2] > sm[3] ? sm[2] : sm[3];
    *flag = ((a > b ? a : b) >= 140) ? 1 : 0;
  }
}

// ---- canonicalize x to bf16 (4M elems, 8 elems/thread) -------------------
__global__ void conv_x(const void* __restrict__ src, u16* __restrict__ dst,
                       const int* __restrict__ flag) {
  const size_t i = ((size_t)blockIdx.x * 256 + threadIdx.x) * 8;
  if (*flag) {
    const float4* f = (const float4*)((const float*)src + i);
    const float4 a = f[0], b = f[1];
    u16x8 o;
    o[0] = f2bf(a.x); o[1] = f2bf(a.y); o[2] = f2bf(a.z); o[3] = f2bf(a.w);
    o[4] = f2bf(b.x); o[5] = f2bf(b.y); o[6] = f2bf(b.z); o[7] = f2bf(b.w);
    *(u16x8*)(dst + i) = o;
  } else {
    *(u16x8*)(dst + i) = *(const u16x8*)((const u16*)src + i);
  }
}

// ---- canonicalize the 6 small vectors (b1|b2|g1|be1|g2|be2 = 9216 elems) --
__global__ void conv_small(const void* b1, const void* b2, const void* g1,
                           const void* be1, const void* g2, const void* be2,
                           u16* __restrict__ dst, const int* __restrict__ flag) {
  const int e = blockIdx.x * 256 + threadIdx.x;
  if (e >= 9216) return;
  const int f = *flag;
  if (e < 4096) {
    dst[e] = ld_cv(b1, e, f);
  } else {
    const int k = (e - 4096) >> 10, off = (e - 4096) & 1023;
    const void* p = (k == 0) ? b2 : (k == 1) ? g1 : (k == 2) ? be1
                    : (k == 3) ? g2 : be2;
    dst[e] = ld_cv(p, off, f);
  }
}

// ---------------- GEMM: C[m][n] = sum_k A[m][k] * BT[n][k] ----------------
template <int EPI>
__launch_bounds__(256)
__global__ void gemm_bt(const u16* __restrict__ A, const u16* __restrict__ B,
                        int K, int N,
                        const u16* __restrict__ bias, const u16* __restrict__ res,
                        void* __restrict__ out,
                        u16* __restrict__ Qo, u16* __restrict__ Ko, u16* __restrict__ Vo,
                        const int* __restrict__ flag) {
  __shared__ __align__(16) u16 As[128 * 32];
  __shared__ __align__(16) u16 Bs[128 * 32];
  const int tid = threadIdx.x;
  const int m0 = blockIdx.y * 128;
  const int n0 = blockIdx.x * 128;
  const int wave = tid >> 6, lane = tid & 63;
  const int wm = (wave >> 1) * 64, wn = (wave & 1) * 64;
  const int lm = lane & 15, lq = lane >> 4;
  const int of32 = (EPI == 2) ? *flag : 0;

  const f32x4 zero = {0.f, 0.f, 0.f, 0.f};
  f32x4 acc[4][4];
#pragma unroll
  for (int i = 0; i < 4; i++)
#pragma unroll
    for (int j = 0; j < 4; j++) acc[i][j] = zero;

  const int ar = tid >> 2;
  const int ac = (tid & 3) * 8;
  const u16* Ag = A + (size_t)(m0 + ar) * K + ac;
  const u16* Bg = B + (size_t)(n0 + ar) * K + ac;
  u16* AsP = &As[tid * 8];
  u16* BsP = &Bs[tid * 8];
  const size_t K64 = (size_t)64 * K;

  for (int k0 = 0; k0 < K; k0 += 32) {
    async16(Ag + k0, AsP);
    async16(Ag + k0 + K64, AsP + 2048);
    async16(Bg + k0, BsP);
    async16(Bg + k0 + K64, BsP + 2048);
    __syncthreads();  // drains vmcnt(0): LDS tile ready
    bf16x8 a[4], b[4];
#pragma unroll
    for (int i = 0; i < 4; i++)
      a[i] = *(const bf16x8*)&As[(wm + i * 16 + lm) * 32 + lq * 8];
#pragma unroll
    for (int i = 0; i < 4; i++)
      b[i] = *(const bf16x8*)&Bs[(wn + i * 16 + lm) * 32 + lq * 8];
#pragma unroll
    for (int i = 0; i < 4; i++)
#pragma unroll
      for (int j = 0; j < 4; j++)
        acc[i][j] = __builtin_amdgcn_mfma_f32_16x16x32_bf16(a[i], b[j], acc[i][j], 0, 0, 0);
    __syncthreads();
  }

#pragma unroll
  for (int i = 0; i < 4; i++) {
#pragma unroll
    for (int r = 0; r < 4; r++) {
      const int row = m0 + wm + i * 16 + lq * 4 + r;
#pragma unroll
      for (int j = 0; j < 4; j++) {
        const int col = n0 + wn + j * 16 + lm;
        const float c = acc[i][j][r];
        if (EPI == 0) {
          const int bb = row >> 11, t = row & 2047;
          const int w = col >> 10, nn = col & 1023;
          const int hh = nn >> 6, e = nn & 63;
          u16* dst = (w == 0) ? Qo : ((w == 1) ? Ko : Vo);
          dst[(((size_t)(bb * 16 + hh)) * 2048 + t) * 64 + e] = f2bf(c);
        } else if (EPI == 1) {
          const float v = c + bf2f(bias[col]);
          ((u16*)out)[(size_t)row * N + col] = f2bf(v > 0.f ? v : 0.f);
        } else {
          const float v = c + bf2f(bias[col]) + bf2f(res[(size_t)row * N + col]);
          if (of32)
            ((float*)out)[(size_t)row * N + col] = v;
          else
            ((u16*)out)[(size_t)row * N + col] = f2bf(v);
        }
      }
    }
  }
}

// ---------------- MFMA flash attention v5: LDS-free, STATIC double-buffer --
// Same algorithm as v4 (S^T = K x Q^T, in-register P as B-fragment under
// key-permutation, per-lane l, no LDS/barriers) but the K/V double-buffer
// uses two NAMED buffer sets with a 2-unrolled loop so every register-array
// index is a compile-time constant. v4's kf[cur] runtime index forced the
// fragments to scratch (WRITE_SIZE 8->175 MB, 28x regression).
__launch_bounds__(128)
__global__ void attn_mfma(const u16* __restrict__ Q, const u16* __restrict__ K,
                          const u16* __restrict__ Vt, const u16* __restrict__ x,
                          u16* __restrict__ x2) {
  const int tid = threadIdx.x;
  const int wave = tid >> 6, lane = tid & 63;
  const int lm = lane & 15, quad = lane >> 4;
  const int gw = blockIdx.x * 2 + wave;
  const int bh = gw >> 6;
  const int qb = 63 - (gw & 63);  // longest-first
  const int qw0 = qb * 32;
  const int b = bh >> 4, h = bh & 15;

  // Q fragments (B-operand): lane holds Q[qw0+s*16+lm][quad*8..+7] (+32)
  bf16x8 qf[2][2];
#pragma unroll
  for (int s = 0; s < 2; s++) {
    const u16* Qp = Q + ((size_t)bh * 2048 + qw0 + s * 16 + lm) * 64 + quad * 8;
    qf[s][0] = *(const bf16x8*)Qp;
    qf[s][1] = *(const bf16x8*)(Qp + 32);
  }
  const f32x4 zero = {0.f, 0.f, 0.f, 0.f};
  f32x4 ot[2][4];
#pragma unroll
  for (int s = 0; s < 2; s++)
#pragma unroll
    for (int j = 0; j < 4; j++) ot[s][j] = zero;
  float l[2] = {0.f, 0.f};

  const u16* Kbh = K + (size_t)bh * 131072;
  const u16* Vbh = Vt + (size_t)bh * 131072;
  const int nt = qb + 1;

  union V8 { bf16x8 v; struct { unsigned long long lo, hi; } q; };
  bf16x8 kfA[2][2], kfB[2][2];
  V8 vfA[4], vfB[4];

  auto loadKV = [&](int ks, bf16x8 (&kfd)[2][2], V8 (&vfd)[4]) {
#pragma unroll
    for (int hh = 0; hh < 2; hh++) {
      const u16* Kp = Kbh + (size_t)(ks + hh * 16 + lm) * 64 + quad * 8;
      kfd[hh][0] = *(const bf16x8*)Kp;
      kfd[hh][1] = *(const bf16x8*)(Kp + 32);
    }
#pragma unroll
    for (int j = 0; j < 4; j++) {
      const u16* Vp = Vbh + (size_t)(j * 16 + lm) * 2048 + ks + quad * 4;
      vfd[j].q.lo = *(const unsigned long long*)Vp;
      vfd[j].q.hi = *(const unsigned long long*)(Vp + 16);
    }
  };

  auto computeTile = [&](int tile, const bf16x8 (&kfc)[2][2], const V8 (&vfc)[4]) {
    // S^T[key][q]
    f32x4 S[2][2];
#pragma unroll
    for (int s = 0; s < 2; s++)
#pragma unroll
      for (int hh = 0; hh < 2; hh++) {
        f32x4 a = zero;
        a = __builtin_amdgcn_mfma_f32_16x16x32_bf16(kfc[hh][0], qf[s][0], a, 0, 0, 0);
        a = __builtin_amdgcn_mfma_f32_16x16x32_bf16(kfc[hh][1], qf[s][1], a, 0, 0, 0);
        S[s][hh] = a;
      }
    const bool lastT = (tile == nt - 1);
#pragma unroll
    for (int s = 0; s < 2; s++) {
      float p[2][4];
#pragma unroll
      for (int hh = 0; hh < 2; hh++)
#pragma unroll
        for (int r = 0; r < 4; r++) {
          float v = __expf(S[s][hh][r] * 0.03125f);
          if (lastT && (hh * 16 + quad * 4 + r > s * 16 + lm)) v = 0.f;
          l[s] += v;
          p[hh][r] = v;
        }
      unsigned pk[4];
      pk[0] = pk_bf16(p[0][1], p[0][0]);
      pk[1] = pk_bf16(p[0][3], p[0][2]);
      pk[2] = pk_bf16(p[1][1], p[1][0]);
      pk[3] = pk_bf16(p[1][3], p[1][2]);
      const bf16x8 pf = *(const bf16x8*)pk;
#pragma unroll
      for (int j = 0; j < 4; j++)
        ot[s][j] = __builtin_amdgcn_mfma_f32_16x16x32_bf16(vfc[j].v, pf, ot[s][j], 0, 0, 0);
    }
  };

  loadKV(0, kfA, vfA);
  for (int tile = 0; tile < nt; tile += 2) {
    if (tile + 1 < nt) loadKV((tile + 1) * 32, kfB, vfB);
    computeTile(tile, kfA, vfA);
    if (tile + 1 >= nt) break;
    if (tile + 2 < nt) loadKV((tile + 2) * 32, kfA, vfA);
    computeTile(tile + 1, kfB, vfB);
  }

  // l lives per-column(q=lm) per-quad; fold the 4 quads
#pragma unroll
  for (int s = 0; s < 2; s++) {
    l[s] += __shfl_xor(l[s], 16);
    l[s] += __shfl_xor(l[s], 32);
  }
  const float linv[2] = {1.f / l[0], 1.f / l[1]};

  // epilogue: x2 = x + O/l.  ot[s][j][r] = O[q=qw0+s*16+lm][e=j*16+quad*4+r]
#pragma unroll
  for (int s = 0; s < 2; s++) {
    const size_t rowbase =
        ((size_t)(b * 2048 + qw0 + s * 16 + lm)) * 1024 + h * 64;
#pragma unroll
    for (int j = 0; j < 4; j++) {
      const int e = j * 16 + quad * 4;
      const ushort4 xv = *(const ushort4*)&x[rowbase + e];
      ushort4 o4;
      o4.x = f2bf(bf2f(xv.x) + ot[s][j][0] * linv[s]);
      o4.y = f2bf(bf2f(xv.y) + ot[s][j][1] * linv[s]);
      o4.z = f2bf(bf2f(xv.z) + ot[s][j][2] * linv[s]);
      o4.w = f2bf(bf2f(xv.w) + ot[s][j][3] * linv[s]);
      *(ushort4*)&x2[rowbase + e] = o4;
    }
  }
}

// ---------------- LayerNorm (ddof=1, eps=1e-5) ----------------------------
__launch_bounds__(256)
__global__ void ln_kernel(const u16* __restrict__ x, const u16* __restrict__ gamma,
                          const u16* __restrict__ beta, u16* __restrict__ out) {
  const size_t row = blockIdx.x;
  const int tid = threadIdx.x;
  const u16* xr = x + row * 1024;
  const ushort4 u = *(const ushort4*)&xr[tid * 4];
  const float v0 = bf2f(u.x), v1 = bf2f(u.y), v2 = bf2f(u.z), v3 = bf2f(u.w);
  float s = v0 + v1 + v2 + v3;
  float sq = v0 * v0 + v1 * v1 + v2 * v2 + v3 * v3;
#pragma unroll
  for (int off = 32; off > 0; off >>= 1) {
    s += __shfl_down(s, off);
    sq += __shfl_down(sq, off);
  }
  __shared__ float ss[4], ssq[4];
  if ((tid & 63) == 0) { ss[tid >> 6] = s; ssq[tid >> 6] = sq; }
  __syncthreads();
  s = ss[0] + ss[1] + ss[2] + ss[3];
  sq = ssq[0] + ssq[1] + ssq[2] + ssq[3];
  const float mean = s * (1.f / 1024.f);
  const float var = (sq - 1024.f * mean * mean) * (1.f / 1023.f);
  const float rs = rsqrtf(var + 1e-5f);
  const ushort4 g = *(const ushort4*)&gamma[tid * 4];
  const ushort4 be = *(const ushort4*)&beta[tid * 4];
  ushort4 o;
  o.x = f2bf(bf2f(g.x) * (v0 - mean) * rs + bf2f(be.x));
  o.y = f2bf(bf2f(g.y) * (v1 - mean) * rs + bf2f(be.y));
  o.z = f2bf(bf2f(g.z) * (v2 - mean) * rs + bf2f(be.z));
  o.w = f2bf(bf2f(g.w) * (v3 - mean) * rs + bf2f(be.w));
  *(ushort4*)&out[row * 1024 + tid * 4] = o;
}

// WT[w*1024+h*64+e][d] = W_w[h][d][e]; coalesced 64x64 LDS tiles.
// grid (16 d-tiles, 48 = w*16+h)
__global__ void transpose_qkv2(const void* __restrict__ Wq, const void* __restrict__ Wk,
                               const void* __restrict__ Wv, u16* __restrict__ WT,
                               const int* __restrict__ flag) {
  __shared__ u16 tile[64][65];
  const int f = *flag;
  const int wh = blockIdx.y;
  const int w = wh >> 4, hh = wh & 15;
  const int tr = blockIdx.x * 64;  // d-range
  const void* W = (w == 0) ? Wq : ((w == 1) ? Wk : Wv);
  const size_t hbase = (size_t)hh * 65536;
  const int lx = threadIdx.x & 63, ly = threadIdx.x >> 6;
#pragma unroll
  for (int i = 0; i < 16; i++)
    tile[ly * 16 + i][lx] = ld_cv(W, hbase + (size_t)(tr + ly * 16 + i) * 64 + lx, f);
  __syncthreads();
#pragma unroll
  for (int i = 0; i < 16; i++)
    WT[((size_t)(w * 1024 + hh * 64 + ly * 16 + i)) * 1024 + tr + lx] =
        tile[lx][ly * 16 + i];
}

// dst[c*R + r] = src[r*C + c], 64x64 LDS tiles, grid (C/64, R/64), dual read
__global__ void transpose_tile(const void* __restrict__ src, u16* __restrict__ dst,
                               int R, int C, const int* __restrict__ flag) {
  __shared__ u16 tile[64][65];
  const int f = *flag;
  const int tc = blockIdx.x * 64, tr = blockIdx.y * 64;
  const int lx = threadIdx.x & 63, ly = threadIdx.x >> 6;
#pragma unroll
  for (int i = 0; i < 16; i++)
    tile[ly * 16 + i][lx] = ld_cv(src, (size_t)(tr + ly * 16 + i) * C + tc + lx, f);
  __syncthreads();
#pragma unroll
  for (int i = 0; i < 16; i++)
    dst[(size_t)(tc + ly * 16 + i) * R + tr + lx] = tile[lx][ly * 16 + i];
}

// V [bh][t][64] -> Vt [bh][e][t], batched coalesced transpose
__global__ void transpose_v(const u16* __restrict__ src, u16* __restrict__ dst) {
  __shared__ u16 tile[64][65];
  const int bh = blockIdx.y;
  const int tt = blockIdx.x * 64;
  const int lx = threadIdx.x & 63, ly = threadIdx.x >> 6;
#pragma unroll
  for (int i = 0; i < 16; i++)
    tile[ly * 16 + i][lx] = src[((size_t)bh * 2048 + tt + ly * 16 + i) * 64 + lx];
  __syncthreads();
#pragma unroll
  for (int i = 0; i < 16; i++)
    dst[((size_t)bh * 64 + ly * 16 + i) * 2048 + tt + lx] = tile[lx][ly * 16 + i];
}

extern "C" void kernel_launch(void* const* d_in, const int* in_sizes, int n_in,
                              void* d_out, int out_size, void* d_ws, size_t ws_size,
                              hipStream_t stream) {
  const void* x      = d_in[0];
  const void* Wq     = d_in[1];
  const void* Wk     = d_in[2];
  const void* Wv     = d_in[3];
  const void* W1     = d_in[4];
  const void* b1     = d_in[5];
  const void* W2     = d_in[6];
  const void* b2     = d_in[7];
  const void* gamma1 = d_in[8];
  const void* beta1  = d_in[9];
  const void* gamma2 = d_in[10];
  const void* beta2  = d_in[11];
  u16* ws = (u16*)d_ws;

  const size_t M4 = 4194304;
  u16* h   = ws;
  u16* Vtb = ws;
  u16* Qb  = ws + 1 * M4;
  u16* Kb  = ws + 2 * M4;
  u16* Vb  = ws + 3 * M4;
  u16* WTq = ws + 4 * M4;
  u16* x2  = ws + 4 * M4;
  u16* Xc  = ws + 5 * M4;
  u16* h2  = ws + 5 * M4;
  u16* W1T = ws + 6 * M4;
  u16* W2T = ws + 7 * M4;
  u16* ff1 = ws;
  u16* smallc = ws + 8 * M4;
  u16* b1c = smallc, *b2c = smallc + 4096, *g1c = smallc + 5120,
     *be1c = smallc + 6144, *g2c = smallc + 7168, *be2c = smallc + 8192;
  int* flag = (int*)(ws + 8 * M4 + 9216);

  sniff_kernel<<<1, 256, 0, stream>>>((const u16*)x, flag);
  conv_x<<<2048, 256, 0, stream>>>(x, Xc, flag);
  conv_small<<<36, 256, 0, stream>>>(b1, b2, gamma1, beta1, gamma2, beta2,
                                     smallc, flag);
  transpose_qkv2<<<dim3(16, 48), 256, 0, stream>>>(Wq, Wk, Wv, WTq, flag);
  transpose_tile<<<dim3(64, 16), 256, 0, stream>>>(W1, W1T, 1024, 4096, flag);
  transpose_tile<<<dim3(16, 64), 256, 0, stream>>>(W2, W2T, 4096, 1024, flag);
  ln_kernel<<<4096, 256, 0, stream>>>(Xc, g1c, be1c, h);
  gemm_bt<0><<<dim3(24, 32), 256, 0, stream>>>(h, WTq, 1024, 3072,
                                               nullptr, nullptr, nullptr,
                                               Qb, Kb, Vb, flag);
  transpose_v<<<dim3(32, 32), 256, 0, stream>>>(Vb, Vtb);
  attn_mfma<<<1024, 128, 0, stream>>>(Qb, Kb, Vtb, Xc, x2);
  ln_kernel<<<4096, 256, 0, stream>>>(x2, g2c, be2c, h2);
  gemm_bt<1><<<dim3(32, 32), 256, 0, stream>>>(h2, W1T, 1024, 4096,
                                               b1c, nullptr, ff1,
                                               nullptr, nullptr, nullptr, flag);
  gemm_bt<2><<<dim3(8, 32), 256, 0, stream>>>(ff1, W2T, 4096, 1024,
                                              b2c, x2, d_out,
                                              nullptr, nullptr, nullptr, flag);
}

// Round 8
// 447.231 us; speedup vs baseline: 8.3674x; 1.1661x over previous
//
#include <hip/hip_runtime.h>

typedef unsigned short u16;
typedef __bf16 bf16;
typedef __attribute__((ext_vector_type(8))) __bf16 bf16x8;
typedef __attribute__((ext_vector_type(4))) float f32x4;
typedef __attribute__((ext_vector_type(8))) unsigned short u16x8;

__device__ __forceinline__ float bf2f(u16 h) {
  return __uint_as_float(((unsigned int)h) << 16);
}
__device__ __forceinline__ u16 f2bf(float f) {
  unsigned int u = __float_as_uint(f);
  return (u16)((u + 0x7fffu + ((u >> 16) & 1u)) >> 16);
}
// dual-dtype scalar read -> bf16 bits
__device__ __forceinline__ u16 ld_cv(const void* p, size_t i, int f32) {
  return f32 ? f2bf(((const float*)p)[i]) : ((const u16*)p)[i];
}
// async global->LDS, 16B per lane; LDS dest = wave-uniform base + lane*16.
__device__ __forceinline__ void async16(const u16* g, u16* l) {
  __builtin_amdgcn_global_load_lds(
      (const __attribute__((address_space(1))) unsigned int*)g,
      (__attribute__((address_space(3))) unsigned int*)l, 16, 0, 0);
}
// pack two fp32 -> two bf16 (round-to-nearest-ish via +0x8000, then v_perm)
__device__ __forceinline__ unsigned pk_bf16(float hi, float lo) {
  return __builtin_amdgcn_perm(__float_as_uint(hi) + 0x8000u,
                               __float_as_uint(lo) + 0x8000u, 0x07060302u);
}

// ---- dtype sniffer: even u16s of fp32 data are mantissa garbage ----------
__global__ void sniff_kernel(const u16* __restrict__ x, int* __restrict__ flag) {
  const int tid = threadIdx.x;
  int me = 0;
#pragma unroll
  for (int j = 0; j < 4; j++) {
    const u16 v = x[(tid * 4 + j) * 2];
    const int e = (v >> 7) & 0xFF;
    me = me > e ? me : e;
  }
#pragma unroll
  for (int off = 32; off > 0; off >>= 1) {
    const int o = __shfl_down(me, off);
    me = me > o ? me : o;
  }
  __shared__ int sm[4];
  if ((tid & 63) == 0) sm[tid >> 6] = me;
  __syncthreads();
  if (tid == 0) {
    int a = sm[0] > sm[1] ? sm[0] : sm[1];
    int b = sm[2] > sm[3] ? sm[2] : sm[3];
    *flag = ((a > b ? a : b) >= 140) ? 1 : 0;
  }
}

// ---- canonicalize x to bf16 (4M elems, 8 elems/thread) -------------------
__global__ void conv_x(const void* __restrict__ src, u16* __restrict__ dst,
                       const int* __restrict__ flag) {
  const size_t i = ((size_t)blockIdx.x * 256 + threadIdx.x) * 8;
  if (*flag) {
    const float4* f = (const float4*)((const float*)src + i);
    const float4 a = f[0], b = f[1];
    u16x8 o;
    o[0] = f2bf(a.x); o[1] = f2bf(a.y); o[2] = f2bf(a.z); o[3] = f2bf(a.w);
    o[4] = f2bf(b.x); o[5] = f2bf(b.y); o[6] = f2bf(b.z); o[7] = f2bf(b.w);
    *(u16x8*)(dst + i) = o;
  } else {
    *(u16x8*)(dst + i) = *(const u16x8*)((const u16*)src + i);
  }
}

// ---- canonicalize the 6 small vectors (b1|b2|g1|be1|g2|be2 = 9216 elems) --
__global__ void conv_small(const void* b1, const void* b2, const void* g1,
                           const void* be1, const void* g2, const void* be2,
                           u16* __restrict__ dst, const int* __restrict__ flag) {
  const int e = blockIdx.x * 256 + threadIdx.x;
  if (e >= 9216) return;
  const int f = *flag;
  if (e < 4096) {
    dst[e] = ld_cv(b1, e, f);
  } else {
    const int k = (e - 4096) >> 10, off = (e - 4096) & 1023;
    const void* p = (k == 0) ? b2 : (k == 1) ? g1 : (k == 2) ? be1
                    : (k == 3) ? g2 : be2;
    dst[e] = ld_cv(p, off, f);
  }
}

// ---------------- GEMM: C[m][n] = sum_k A[m][k] * BT[n][k] ----------------
template <int EPI>
__launch_bounds__(256)
__global__ void gemm_bt(const u16* __restrict__ A, const u16* __restrict__ B,
                        int K, int N,
                        const u16* __restrict__ bias, const u16* __restrict__ res,
                        void* __restrict__ out,
                        u16* __restrict__ Qo, u16* __restrict__ Ko, u16* __restrict__ Vo,
                        const int* __restrict__ flag) {
  __shared__ __align__(16) u16 As[128 * 32];
  __shared__ __align__(16) u16 Bs[128 * 32];
  const int tid = threadIdx.x;
  const int m0 = blockIdx.y * 128;
  const int n0 = blockIdx.x * 128;
  const int wave = tid >> 6, lane = tid & 63;
  const int wm = (wave >> 1) * 64, wn = (wave & 1) * 64;
  const int lm = lane & 15, lq = lane >> 4;
  const int of32 = (EPI == 2) ? *flag : 0;

  const f32x4 zero = {0.f, 0.f, 0.f, 0.f};
  f32x4 acc[4][4];
#pragma unroll
  for (int i = 0; i < 4; i++)
#pragma unroll
    for (int j = 0; j < 4; j++) acc[i][j] = zero;

  const int ar = tid >> 2;
  const int ac = (tid & 3) * 8;
  const u16* Ag = A + (size_t)(m0 + ar) * K + ac;
  const u16* Bg = B + (size_t)(n0 + ar) * K + ac;
  u16* AsP = &As[tid * 8];
  u16* BsP = &Bs[tid * 8];
  const size_t K64 = (size_t)64 * K;

  for (int k0 = 0; k0 < K; k0 += 32) {
    async16(Ag + k0, AsP);
    async16(Ag + k0 + K64, AsP + 2048);
    async16(Bg + k0, BsP);
    async16(Bg + k0 + K64, BsP + 2048);
    __syncthreads();  // drains vmcnt(0): LDS tile ready
    bf16x8 a[4], b[4];
#pragma unroll
    for (int i = 0; i < 4; i++)
      a[i] = *(const bf16x8*)&As[(wm + i * 16 + lm) * 32 + lq * 8];
#pragma unroll
    for (int i = 0; i < 4; i++)
      b[i] = *(const bf16x8*)&Bs[(wn + i * 16 + lm) * 32 + lq * 8];
#pragma unroll
    for (int i = 0; i < 4; i++)
#pragma unroll
      for (int j = 0; j < 4; j++)
        acc[i][j] = __builtin_amdgcn_mfma_f32_16x16x32_bf16(a[i], b[j], acc[i][j], 0, 0, 0);
    __syncthreads();
  }

#pragma unroll
  for (int i = 0; i < 4; i++) {
#pragma unroll
    for (int r = 0; r < 4; r++) {
      const int row = m0 + wm + i * 16 + lq * 4 + r;
#pragma unroll
      for (int j = 0; j < 4; j++) {
        const int col = n0 + wn + j * 16 + lm;
        const float c = acc[i][j][r];
        if (EPI == 0) {
          const int bb = row >> 11, t = row & 2047;
          const int w = col >> 10, nn = col & 1023;
          const int hh = nn >> 6, e = nn & 63;
          u16* dst = (w == 0) ? Qo : ((w == 1) ? Ko : Vo);
          dst[(((size_t)(bb * 16 + hh)) * 2048 + t) * 64 + e] = f2bf(c);
        } else if (EPI == 1) {
          const float v = c + bf2f(bias[col]);
          ((u16*)out)[(size_t)row * N + col] = f2bf(v > 0.f ? v : 0.f);
        } else {
          const float v = c + bf2f(bias[col]) + bf2f(res[(size_t)row * N + col]);
          if (of32)
            ((float*)out)[(size_t)row * N + col] = v;
          else
            ((u16*)out)[(size_t)row * N + col] = f2bf(v);
        }
      }
    }
  }
}

// ---------------- MFMA flash attention v6: split-K + XCD affinity ----------
// Block = one (bh, q-block of 32). 4 waves split the key range 4 ways (<=16
// tiles each); static-max-0 softmax makes partials (O,l) additive, so merge
// is one LDS reduce after a single barrier. bid&7 == bh&7 pins each bh's K/V
// to one XCD's L2 (2 MB working set < 4 MB). Longest q-blocks launch first.
// Per-wave: S^T = K x Q^T (C-layout col=q), in-register P as B-fragment
// (key-permutation consistent with Vt A-fragment), static double buffer.
__launch_bounds__(256)
__global__ void attn_mfma(const u16* __restrict__ Q, const u16* __restrict__ K,
                          const u16* __restrict__ Vt, const u16* __restrict__ x,
                          u16* __restrict__ x2) {
  __shared__ __align__(16) float Olds[4][32][68];
  __shared__ float Llds[4][2][16];
  const int tid = threadIdx.x;
  const int wave = tid >> 6, lane = tid & 63;
  const int lm = lane & 15, quad = lane >> 4;
  const int bid = blockIdx.x;
  const int xcd = bid & 7, jj = bid >> 3;
  const int bh = xcd + 8 * (jj & 3);
  const int qb = 63 - (jj >> 2);  // longest-first within each XCD stream
  const int qw0 = qb * 32;
  const int b = bh >> 4, h = bh & 15;

  // Q fragments (B-operand): lane holds Q[qw0+s*16+lm][quad*8..+7] (+32)
  bf16x8 qf[2][2];
#pragma unroll
  for (int s = 0; s < 2; s++) {
    const u16* Qp = Q + ((size_t)bh * 2048 + qw0 + s * 16 + lm) * 64 + quad * 8;
    qf[s][0] = *(const bf16x8*)Qp;
    qf[s][1] = *(const bf16x8*)(Qp + 32);
  }
  const f32x4 zero = {0.f, 0.f, 0.f, 0.f};
  f32x4 ot[2][4];
#pragma unroll
  for (int s = 0; s < 2; s++)
#pragma unroll
    for (int j = 0; j < 4; j++) ot[s][j] = zero;
  float l[2] = {0.f, 0.f};

  const u16* Kbh = K + (size_t)bh * 131072;
  const u16* Vbh = Vt + (size_t)bh * 131072;
  const int nt = qb + 1;
  const int cw = (nt + 3) >> 2;            // tiles per wave
  const int t0 = wave * cw;
  const int t1e = t0 + cw;
  const int t1 = (t1e < nt) ? t1e : nt;

  union V8 { bf16x8 v; struct { unsigned long long lo, hi; } q; };
  bf16x8 kfA[2][2], kfB[2][2];
  V8 vfA[4], vfB[4];

  auto loadKV = [&](int ks, bf16x8 (&kfd)[2][2], V8 (&vfd)[4]) {
#pragma unroll
    for (int hh = 0; hh < 2; hh++) {
      const u16* Kp = Kbh + (size_t)(ks + hh * 16 + lm) * 64 + quad * 8;
      kfd[hh][0] = *(const bf16x8*)Kp;
      kfd[hh][1] = *(const bf16x8*)(Kp + 32);
    }
#pragma unroll
    for (int j = 0; j < 4; j++) {
      const u16* Vp = Vbh + (size_t)(j * 16 + lm) * 2048 + ks + quad * 4;
      vfd[j].q.lo = *(const unsigned long long*)Vp;
      vfd[j].q.hi = *(const unsigned long long*)(Vp + 16);
    }
  };

  auto computeTile = [&](int t, const bf16x8 (&kfc)[2][2], const V8 (&vfc)[4]) {
    f32x4 S[2][2];
#pragma unroll
    for (int s = 0; s < 2; s++)
#pragma unroll
      for (int hh = 0; hh < 2; hh++) {
        f32x4 a = zero;
        a = __builtin_amdgcn_mfma_f32_16x16x32_bf16(kfc[hh][0], qf[s][0], a, 0, 0, 0);
        a = __builtin_amdgcn_mfma_f32_16x16x32_bf16(kfc[hh][1], qf[s][1], a, 0, 0, 0);
        S[s][hh] = a;
      }
    const bool maskT = (t == qb);  // diagonal tile only
#pragma unroll
    for (int s = 0; s < 2; s++) {
      float p[2][4];
#pragma unroll
      for (int hh = 0; hh < 2; hh++)
#pragma unroll
        for (int r = 0; r < 4; r++) {
          float v = __expf(S[s][hh][r] * 0.03125f);
          if (maskT && (hh * 16 + quad * 4 + r > s * 16 + lm)) v = 0.f;
          l[s] += v;
          p[hh][r] = v;
        }
      unsigned pk[4];
      pk[0] = pk_bf16(p[0][1], p[0][0]);
      pk[1] = pk_bf16(p[0][3], p[0][2]);
      pk[2] = pk_bf16(p[1][1], p[1][0]);
      pk[3] = pk_bf16(p[1][3], p[1][2]);
      const bf16x8 pf = *(const bf16x8*)pk;
#pragma unroll
      for (int j = 0; j < 4; j++)
        ot[s][j] = __builtin_amdgcn_mfma_f32_16x16x32_bf16(vfc[j].v, pf, ot[s][j], 0, 0, 0);
    }
  };

  if (t0 < t1) {
    loadKV(t0 * 32, kfA, vfA);
    for (int t = t0; t < t1; t += 2) {
      if (t + 1 < t1) loadKV((t + 1) * 32, kfB, vfB);
      computeTile(t, kfA, vfA);
      if (t + 1 >= t1) break;
      if (t + 2 < t1) loadKV((t + 2) * 32, kfA, vfA);
      computeTile(t + 1, kfB, vfB);
    }
  }

  // fold l across the 4 quads (per column q=lm)
#pragma unroll
  for (int s = 0; s < 2; s++) {
    l[s] += __shfl_xor(l[s], 16);
    l[s] += __shfl_xor(l[s], 32);
  }

  // write partials: ot[s][j][r] = O[q=s*16+lm][e=j*16+quad*4+r]
#pragma unroll
  for (int s = 0; s < 2; s++)
#pragma unroll
    for (int j = 0; j < 4; j++)
      *(f32x4*)&Olds[wave][s * 16 + lm][j * 16 + quad * 4] = ot[s][j];
  if (quad == 0) {
    Llds[wave][0][lm] = l[0];
    Llds[wave][1][lm] = l[1];
  }
  __syncthreads();

  // merge 4 partials + residual epilogue. thread -> (q, 8-elem chunk)
  const int q = tid >> 3;
  const int e0 = (tid & 7) * 8;
  f32x4 oa = zero, ob = zero;
#pragma unroll
  for (int w = 0; w < 4; w++) {
    oa += *(const f32x4*)&Olds[w][q][e0];
    ob += *(const f32x4*)&Olds[w][q][e0 + 4];
  }
  const float lt = Llds[0][q >> 4][q & 15] + Llds[1][q >> 4][q & 15] +
                   Llds[2][q >> 4][q & 15] + Llds[3][q >> 4][q & 15];
  const float linv = 1.f / lt;
  const size_t rowbase = ((size_t)(b * 2048 + qw0 + q)) * 1024 + h * 64 + e0;
  const u16x8 xv = *(const u16x8*)&x[rowbase];
  u16x8 o8;
#pragma unroll
  for (int k = 0; k < 4; k++) o8[k] = f2bf(bf2f(xv[k]) + oa[k] * linv);
#pragma unroll
  for (int k = 0; k < 4; k++) o8[4 + k] = f2bf(bf2f(xv[4 + k]) + ob[k] * linv);
  *(u16x8*)&x2[rowbase] = o8;
}

// ---------------- LayerNorm (ddof=1, eps=1e-5) ----------------------------
__launch_bounds__(256)
__global__ void ln_kernel(const u16* __restrict__ x, const u16* __restrict__ gamma,
                          const u16* __restrict__ beta, u16* __restrict__ out) {
  const size_t row = blockIdx.x;
  const int tid = threadIdx.x;
  const u16* xr = x + row * 1024;
  const ushort4 u = *(const ushort4*)&xr[tid * 4];
  const float v0 = bf2f(u.x), v1 = bf2f(u.y), v2 = bf2f(u.z), v3 = bf2f(u.w);
  float s = v0 + v1 + v2 + v3;
  float sq = v0 * v0 + v1 * v1 + v2 * v2 + v3 * v3;
#pragma unroll
  for (int off = 32; off > 0; off >>= 1) {
    s += __shfl_down(s, off);
    sq += __shfl_down(sq, off);
  }
  __shared__ float ss[4], ssq[4];
  if ((tid & 63) == 0) { ss[tid >> 6] = s; ssq[tid >> 6] = sq; }
  __syncthreads();
  s = ss[0] + ss[1] + ss[2] + ss[3];
  sq = ssq[0] + ssq[1] + ssq[2] + ssq[3];
  const float mean = s * (1.f / 1024.f);
  const float var = (sq - 1024.f * mean * mean) * (1.f / 1023.f);
  const float rs = rsqrtf(var + 1e-5f);
  const ushort4 g = *(const ushort4*)&gamma[tid * 4];
  const ushort4 be = *(const ushort4*)&beta[tid * 4];
  ushort4 o;
  o.x = f2bf(bf2f(g.x) * (v0 - mean) * rs + bf2f(be.x));
  o.y = f2bf(bf2f(g.y) * (v1 - mean) * rs + bf2f(be.y));
  o.z = f2bf(bf2f(g.z) * (v2 - mean) * rs + bf2f(be.z));
  o.w = f2bf(bf2f(g.w) * (v3 - mean) * rs + bf2f(be.w));
  *(ushort4*)&out[row * 1024 + tid * 4] = o;
}

// WT[w*1024+h*64+e][d] = W_w[h][d][e]; coalesced 64x64 LDS tiles.
// grid (16 d-tiles, 48 = w*16+h)
__global__ void transpose_qkv2(const void* __restrict__ Wq, const void* __restrict__ Wk,
                               const void* __restrict__ Wv, u16* __restrict__ WT,
                               const int* __restrict__ flag) {
  __shared__ u16 tile[64][65];
  const int f = *flag;
  const int wh = blockIdx.y;
  const int w = wh >> 4, hh = wh & 15;
  const int tr = blockIdx.x * 64;  // d-range
  const void* W = (w == 0) ? Wq : ((w == 1) ? Wk : Wv);
  const size_t hbase = (size_t)hh * 65536;
  const int lx = threadIdx.x & 63, ly = threadIdx.x >> 6;
#pragma unroll
  for (int i = 0; i < 16; i++)
    tile[ly * 16 + i][lx] = ld_cv(W, hbase + (size_t)(tr + ly * 16 + i) * 64 + lx, f);
  __syncthreads();
#pragma unroll
  for (int i = 0; i < 16; i++)
    WT[((size_t)(w * 1024 + hh * 64 + ly * 16 + i)) * 1024 + tr + lx] =
        tile[lx][ly * 16 + i];
}

// dst[c*R + r] = src[r*C + c], 64x64 LDS tiles, grid (C/64, R/64), dual read
__global__ void transpose_tile(const void* __restrict__ src, u16* __restrict__ dst,
                               int R, int C, const int* __restrict__ flag) {
  __shared__ u16 tile[64][65];
  const int f = *flag;
  const int tc = blockIdx.x * 64, tr = blockIdx.y * 64;
  const int lx = threadIdx.x & 63, ly = threadIdx.x >> 6;
#pragma unroll
  for (int i = 0; i < 16; i++)
    tile[ly * 16 + i][lx] = ld_cv(src, (size_t)(tr + ly * 16 + i) * C + tc + lx, f);
  __syncthreads();
#pragma unroll
  for (int i = 0; i < 16; i++)
    dst[(size_t)(tc + ly * 16 + i) * R + tr + lx] = tile[lx][ly * 16 + i];
}

// V [bh][t][64] -> Vt [bh][e][t], batched coalesced transpose
__global__ void transpose_v(const u16* __restrict__ src, u16* __restrict__ dst) {
  __shared__ u16 tile[64][65];
  const int bh = blockIdx.y;
  const int tt = blockIdx.x * 64;
  const int lx = threadIdx.x & 63, ly = threadIdx.x >> 6;
#pragma unroll
  for (int i = 0; i < 16; i++)
    tile[ly * 16 + i][lx] = src[((size_t)bh * 2048 + tt + ly * 16 + i) * 64 + lx];
  __syncthreads();
#pragma unroll
  for (int i = 0; i < 16; i++)
    dst[((size_t)bh * 64 + ly * 16 + i) * 2048 + tt + lx] = tile[lx][ly * 16 + i];
}

extern "C" void kernel_launch(void* const* d_in, const int* in_sizes, int n_in,
                              void* d_out, int out_size, void* d_ws, size_t ws_size,
                              hipStream_t stream) {
  const void* x      = d_in[0];
  const void* Wq     = d_in[1];
  const void* Wk     = d_in[2];
  const void* Wv     = d_in[3];
  const void* W1     = d_in[4];
  const void* b1     = d_in[5];
  const void* W2     = d_in[6];
  const void* b2     = d_in[7];
  const void* gamma1 = d_in[8];
  const void* beta1  = d_in[9];
  const void* gamma2 = d_in[10];
  const void* beta2  = d_in[11];
  u16* ws = (u16*)d_ws;

  const size_t M4 = 4194304;
  u16* h   = ws;
  u16* Vtb = ws;
  u16* Qb  = ws + 1 * M4;
  u16* Kb  = ws + 2 * M4;
  u16* Vb  = ws + 3 * M4;
  u16* WTq = ws + 4 * M4;
  u16* x2  = ws + 4 * M4;
  u16* Xc  = ws + 5 * M4;
  u16* h2  = ws + 5 * M4;
  u16* W1T = ws + 6 * M4;
  u16* W2T = ws + 7 * M4;
  u16* ff1 = ws;
  u16* smallc = ws + 8 * M4;
  u16* b1c = smallc, *b2c = smallc + 4096, *g1c = smallc + 5120,
     *be1c = smallc + 6144, *g2c = smallc + 7168, *be2c = smallc + 8192;
  int* flag = (int*)(ws + 8 * M4 + 9216);

  sniff_kernel<<<1, 256, 0, stream>>>((const u16*)x, flag);
  conv_x<<<2048, 256, 0, stream>>>(x, Xc, flag);
  conv_small<<<36, 256, 0, stream>>>(b1, b2, gamma1, beta1, gamma2, beta2,
                                     smallc, flag);
  transpose_qkv2<<<dim3(16, 48), 256, 0, stream>>>(Wq, Wk, Wv, WTq, flag);
  transpose_tile<<<dim3(64, 16), 256, 0, stream>>>(W1, W1T, 1024, 4096, flag);
  transpose_tile<<<dim3(16, 64), 256, 0, stream>>>(W2, W2T, 4096, 1024, flag);
  ln_kernel<<<4096, 256, 0, stream>>>(Xc, g1c, be1c, h);
  gemm_bt<0><<<dim3(24, 32), 256, 0, stream>>>(h, WTq, 1024, 3072,
                                               nullptr, nullptr, nullptr,
                                               Qb, Kb, Vb, flag);
  transpose_v<<<dim3(32, 32), 256, 0, stream>>>(Vb, Vtb);
  attn_mfma<<<2048, 256, 0, stream>>>(Qb, Kb, Vtb, Xc, x2);
  ln_kernel<<<4096, 256, 0, stream>>>(x2, g2c, be2c, h2);
  gemm_bt<1><<<dim3(32, 32), 256, 0, stream>>>(h2, W1T, 1024, 4096,
                                               b1c, nullptr, ff1,
                                               nullptr, nullptr, nullptr, flag);
  gemm_bt<2><<<dim3(8, 32), 256, 0, stream>>>(ff1, W2T, 4096, 1024,
                                              b2c, x2, d_out,
                                              nullptr, nullptr, nullptr, flag);
}

// Round 9
// 423.208 us; speedup vs baseline: 8.8424x; 1.0568x over previous
//
#include <hip/hip_runtime.h>

typedef unsigned short u16;
typedef __bf16 bf16;
typedef __attribute__((ext_vector_type(8))) __bf16 bf16x8;
typedef __attribute__((ext_vector_type(4))) float f32x4;
typedef __attribute__((ext_vector_type(8))) unsigned short u16x8;

__device__ __forceinline__ float bf2f(u16 h) {
  return __uint_as_float(((unsigned int)h) << 16);
}
__device__ __forceinline__ u16 f2bf(float f) {
  unsigned int u = __float_as_uint(f);
  return (u16)((u + 0x7fffu + ((u >> 16) & 1u)) >> 16);
}
__device__ __forceinline__ u16 ld_cv(const void* p, size_t i, int f32) {
  return f32 ? f2bf(((const float*)p)[i]) : ((const u16*)p)[i];
}
__device__ __forceinline__ void async16(const u16* g, u16* l) {
  __builtin_amdgcn_global_load_lds(
      (const __attribute__((address_space(1))) unsigned int*)g,
      (__attribute__((address_space(3))) unsigned int*)l, 16, 0, 0);
}
__device__ __forceinline__ unsigned pk_bf16(float hi, float lo) {
  return __builtin_amdgcn_perm(__float_as_uint(hi) + 0x8000u,
                               __float_as_uint(lo) + 0x8000u, 0x07060302u);
}

// ---- dtype sniffer ------------------------------------------------------
__global__ void sniff_kernel(const u16* __restrict__ x, int* __restrict__ flag) {
  const int tid = threadIdx.x;
  int me = 0;
#pragma unroll
  for (int j = 0; j < 4; j++) {
    const u16 v = x[(tid * 4 + j) * 2];
    const int e = (v >> 7) & 0xFF;
    me = me > e ? me : e;
  }
#pragma unroll
  for (int off = 32; off > 0; off >>= 1) {
    const int o = __shfl_down(me, off);
    me = me > o ? me : o;
  }
  __shared__ int sm[4];
  if ((tid & 63) == 0) sm[tid >> 6] = me;
  __syncthreads();
  if (tid == 0) {
    int a = sm[0] > sm[1] ? sm[0] : sm[1];
    int b = sm[2] > sm[3] ? sm[2] : sm[3];
    *flag = ((a > b ? a : b) >= 140) ? 1 : 0;
  }
}

// ---- canonicalize the 6 small vectors (b1|b2|g1|be1|g2|be2) --------------
__global__ void conv_small(const void* b1, const void* b2, const void* g1,
                           const void* be1, const void* g2, const void* be2,
                           u16* __restrict__ dst, const int* __restrict__ flag) {
  const int e = blockIdx.x * 256 + threadIdx.x;
  if (e >= 9216) return;
  const int f = *flag;
  if (e < 4096) {
    dst[e] = ld_cv(b1, e, f);
  } else {
    const int k = (e - 4096) >> 10, off = (e - 4096) & 1023;
    const void* p = (k == 0) ? b2 : (k == 1) ? g1 : (k == 2) ? be1
                    : (k == 3) ? g2 : be2;
    dst[e] = ld_cv(p, off, f);
  }
}

// ---------------- GEMM: C[m][n] = sum_k A[m][k] * BT[n][k] ----------------
// Tile BM(=WR*64) x BN(=WC*64), waves WRxWC (each 64x64). BK=64 staged as
// two BK=32 half-tiles (proven layout) sharing ONE barrier pair -> 32 MFMA
// per wave per drain. XCD-affine 1-D grid: xcd=bid&7 owns an n-strip.
template <int EPI, int WR, int WC>
__launch_bounds__(WR * WC * 64)
__global__ void gemm_bt(const u16* __restrict__ A, const u16* __restrict__ B,
                        int K, int NX, int N,
                        const u16* __restrict__ bias, const u16* __restrict__ res,
                        void* __restrict__ out,
                        u16* __restrict__ Qo, u16* __restrict__ Ko, u16* __restrict__ Vo,
                        const int* __restrict__ flag) {
  constexpr int BM = WR * 64, BN = WC * 64, T = WR * WC * 64;
  constexpr int RPA = T / 4;          // rows per async round (BK=32 layout)
  constexpr int RAH = BM / RPA;       // A rounds per k-half
  constexpr int RBH = BN / RPA;       // B rounds per k-half
  __shared__ __align__(16) u16 As[BM * 64];
  __shared__ __align__(16) u16 Bs[BN * 64];
  const int tid = threadIdx.x;
  const int bid = blockIdx.x;
  const int nxp = NX >> 3;
  const int xcd = bid & 7, j9 = bid >> 3;
  const int n0 = (xcd * nxp + j9 % nxp) * BN;
  const int m0 = (j9 / nxp) * BM;
  const int wave = tid >> 6, lane = tid & 63;
  const int wm = (wave / WC) * 64, wn = (wave % WC) * 64;
  const int lm = lane & 15, lq = lane >> 4;
  const int of32 = (EPI == 2) ? *flag : 0;

  const f32x4 zero = {0.f, 0.f, 0.f, 0.f};
  f32x4 acc[4][4];
#pragma unroll
  for (int i = 0; i < 4; i++)
#pragma unroll
    for (int j = 0; j < 4; j++) acc[i][j] = zero;

  const int ar = tid >> 2;            // row within round
  const int ac = (tid & 3) * 8;       // col 0,8,16,24
  const u16* Ag = A + (size_t)(m0 + ar) * K + ac;
  const u16* Bg = B + (size_t)(n0 + ar) * K + ac;
  u16* AsP = &As[tid * 8];
  u16* BsP = &Bs[tid * 8];

  for (int k0 = 0; k0 < K; k0 += 64) {
#pragma unroll
    for (int hh = 0; hh < 2; hh++) {
#pragma unroll
      for (int c = 0; c < RAH; c++)
        async16(Ag + k0 + hh * 32 + (size_t)c * RPA * K,
                AsP + hh * BM * 32 + c * RPA * 32);
#pragma unroll
      for (int c = 0; c < RBH; c++)
        async16(Bg + k0 + hh * 32 + (size_t)c * RPA * K,
                BsP + hh * BN * 32 + c * RPA * 32);
    }
    __syncthreads();  // drains vmcnt(0): both k-halves ready
    bf16x8 a0[4], a1[4], b0[4], b1[4];
#pragma unroll
    for (int i = 0; i < 4; i++) {
      a0[i] = *(const bf16x8*)&As[(wm + i * 16 + lm) * 32 + lq * 8];
      a1[i] = *(const bf16x8*)&As[BM * 32 + (wm + i * 16 + lm) * 32 + lq * 8];
    }
#pragma unroll
    for (int i = 0; i < 4; i++) {
      b0[i] = *(const bf16x8*)&Bs[(wn + i * 16 + lm) * 32 + lq * 8];
      b1[i] = *(const bf16x8*)&Bs[BN * 32 + (wn + i * 16 + lm) * 32 + lq * 8];
    }
#pragma unroll
    for (int i = 0; i < 4; i++)
#pragma unroll
      for (int j = 0; j < 4; j++) {
        acc[i][j] = __builtin_amdgcn_mfma_f32_16x16x32_bf16(a0[i], b0[j], acc[i][j], 0, 0, 0);
        acc[i][j] = __builtin_amdgcn_mfma_f32_16x16x32_bf16(a1[i], b1[j], acc[i][j], 0, 0, 0);
      }
    __syncthreads();  // reads done before next tile overwrites
  }

#pragma unroll
  for (int i = 0; i < 4; i++) {
#pragma unroll
    for (int r = 0; r < 4; r++) {
      const int row = m0 + wm + i * 16 + lq * 4 + r;
#pragma unroll
      for (int j = 0; j < 4; j++) {
        const int col = n0 + wn + j * 16 + lm;
        const float c = acc[i][j][r];
        if (EPI == 0) {
          const int bb = row >> 11, t = row & 2047;
          const int w = col >> 10, nn = col & 1023;
          const int hh = nn >> 6, e = nn & 63;
          u16* dst = (w == 0) ? Qo : ((w == 1) ? Ko : Vo);
          dst[(((size_t)(bb * 16 + hh)) * 2048 + t) * 64 + e] = f2bf(c);
        } else if (EPI == 1) {
          const float v = c + bf2f(bias[col]);
          ((u16*)out)[(size_t)row * N + col] = f2bf(v > 0.f ? v : 0.f);
        } else {
          const float v = c + bf2f(bias[col]) + bf2f(res[(size_t)row * N + col]);
          if (of32)
            ((float*)out)[(size_t)row * N + col] = v;
          else
            ((u16*)out)[(size_t)row * N + col] = f2bf(v);
        }
      }
    }
  }
}

// ---------------- MFMA flash attention: split-K + XCD affinity -------------
__launch_bounds__(256)
__global__ void attn_mfma(const u16* __restrict__ Q, const u16* __restrict__ K,
                          const u16* __restrict__ Vt, const void* __restrict__ xres,
                          const int* __restrict__ flag, u16* __restrict__ x2) {
  __shared__ __align__(16) float Olds[4][32][68];
  __shared__ float Llds[4][2][16];
  const int tid = threadIdx.x;
  const int wave = tid >> 6, lane = tid & 63;
  const int lm = lane & 15, quad = lane >> 4;
  const int bid = blockIdx.x;
  const int xcd = bid & 7, jj = bid >> 3;
  const int bh = xcd + 8 * (jj & 3);
  const int qb = 63 - (jj >> 2);
  const int qw0 = qb * 32;
  const int b = bh >> 4, h = bh & 15;

  bf16x8 qf[2][2];
#pragma unroll
  for (int s = 0; s < 2; s++) {
    const u16* Qp = Q + ((size_t)bh * 2048 + qw0 + s * 16 + lm) * 64 + quad * 8;
    qf[s][0] = *(const bf16x8*)Qp;
    qf[s][1] = *(const bf16x8*)(Qp + 32);
  }
  const f32x4 zero = {0.f, 0.f, 0.f, 0.f};
  f32x4 ot[2][4];
#pragma unroll
  for (int s = 0; s < 2; s++)
#pragma unroll
    for (int j = 0; j < 4; j++) ot[s][j] = zero;
  float l[2] = {0.f, 0.f};

  const u16* Kbh = K + (size_t)bh * 131072;
  const u16* Vbh = Vt + (size_t)bh * 131072;
  const int nt = qb + 1;
  const int cw = (nt + 3) >> 2;
  const int t0 = wave * cw;
  const int t1e = t0 + cw;
  const int t1 = (t1e < nt) ? t1e : nt;

  union V8 { bf16x8 v; struct { unsigned long long lo, hi; } q; };
  bf16x8 kfA[2][2], kfB[2][2];
  V8 vfA[4], vfB[4];

  auto loadKV = [&](int ks, bf16x8 (&kfd)[2][2], V8 (&vfd)[4]) {
#pragma unroll
    for (int hh = 0; hh < 2; hh++) {
      const u16* Kp = Kbh + (size_t)(ks + hh * 16 + lm) * 64 + quad * 8;
      kfd[hh][0] = *(const bf16x8*)Kp;
      kfd[hh][1] = *(const bf16x8*)(Kp + 32);
    }
#pragma unroll
    for (int j = 0; j < 4; j++) {
      const u16* Vp = Vbh + (size_t)(j * 16 + lm) * 2048 + ks + quad * 4;
      vfd[j].q.lo = *(const unsigned long long*)Vp;
      vfd[j].q.hi = *(const unsigned long long*)(Vp + 16);
    }
  };

  auto computeTile = [&](int t, const bf16x8 (&kfc)[2][2], const V8 (&vfc)[4]) {
    f32x4 S[2][2];
#pragma unroll
    for (int s = 0; s < 2; s++)
#pragma unroll
      for (int hh = 0; hh < 2; hh++) {
        f32x4 a = zero;
        a = __builtin_amdgcn_mfma_f32_16x16x32_bf16(kfc[hh][0], qf[s][0], a, 0, 0, 0);
        a = __builtin_amdgcn_mfma_f32_16x16x32_bf16(kfc[hh][1], qf[s][1], a, 0, 0, 0);
        S[s][hh] = a;
      }
    const bool maskT = (t == qb);
#pragma unroll
    for (int s = 0; s < 2; s++) {
      float p[2][4];
#pragma unroll
      for (int hh = 0; hh < 2; hh++)
#pragma unroll
        for (int r = 0; r < 4; r++) {
          float v = __expf(S[s][hh][r] * 0.03125f);
          if (maskT && (hh * 16 + quad * 4 + r > s * 16 + lm)) v = 0.f;
          l[s] += v;
          p[hh][r] = v;
        }
      unsigned pk[4];
      pk[0] = pk_bf16(p[0][1], p[0][0]);
      pk[1] = pk_bf16(p[0][3], p[0][2]);
      pk[2] = pk_bf16(p[1][1], p[1][0]);
      pk[3] = pk_bf16(p[1][3], p[1][2]);
      const bf16x8 pf = *(const bf16x8*)pk;
#pragma unroll
      for (int j = 0; j < 4; j++)
        ot[s][j] = __builtin_amdgcn_mfma_f32_16x16x32_bf16(vfc[j].v, pf, ot[s][j], 0, 0, 0);
    }
  };

  if (t0 < t1) {
    loadKV(t0 * 32, kfA, vfA);
    for (int t = t0; t < t1; t += 2) {
      if (t + 1 < t1) loadKV((t + 1) * 32, kfB, vfB);
      computeTile(t, kfA, vfA);
      if (t + 1 >= t1) break;
      if (t + 2 < t1) loadKV((t + 2) * 32, kfA, vfA);
      computeTile(t + 1, kfB, vfB);
    }
  }

#pragma unroll
  for (int s = 0; s < 2; s++) {
    l[s] += __shfl_xor(l[s], 16);
    l[s] += __shfl_xor(l[s], 32);
  }

#pragma unroll
  for (int s = 0; s < 2; s++)
#pragma unroll
    for (int j = 0; j < 4; j++)
      *(f32x4*)&Olds[wave][s * 16 + lm][j * 16 + quad * 4] = ot[s][j];
  if (quad == 0) {
    Llds[wave][0][lm] = l[0];
    Llds[wave][1][lm] = l[1];
  }
  __syncthreads();

  const int q = tid >> 3;
  const int e0 = (tid & 7) * 8;
  f32x4 oa = zero, ob = zero;
#pragma unroll
  for (int w = 0; w < 4; w++) {
    oa += *(const f32x4*)&Olds[w][q][e0];
    ob += *(const f32x4*)&Olds[w][q][e0 + 4];
  }
  const float lt = Llds[0][q >> 4][q & 15] + Llds[1][q >> 4][q & 15] +
                   Llds[2][q >> 4][q & 15] + Llds[3][q >> 4][q & 15];
  const float linv = 1.f / lt;
  const size_t rowbase = ((size_t)(b * 2048 + qw0 + q)) * 1024 + h * 64 + e0;
  float xv[8];
  if (*flag) {
    const float* xf = (const float*)xres + rowbase;
    const float4 u0 = *(const float4*)xf;
    const float4 u1 = *(const float4*)(xf + 4);
    xv[0] = u0.x; xv[1] = u0.y; xv[2] = u0.z; xv[3] = u0.w;
    xv[4] = u1.x; xv[5] = u1.y; xv[6] = u1.z; xv[7] = u1.w;
  } else {
    const u16x8 u = *(const u16x8*)((const u16*)xres + rowbase);
#pragma unroll
    for (int k = 0; k < 8; k++) xv[k] = bf2f(u[k]);
  }
  u16x8 o8;
#pragma unroll
  for (int k = 0; k < 4; k++) o8[k] = f2bf(xv[k] + oa[k] * linv);
#pragma unroll
  for (int k = 0; k < 4; k++) o8[4 + k] = f2bf(xv[4 + k] + ob[k] * linv);
  *(u16x8*)&x2[rowbase] = o8;
}

// ---------------- LayerNorm (ddof=1, eps=1e-5), dual-dtype source ----------
__launch_bounds__(256)
__global__ void ln_kernel(const void* __restrict__ x, const u16* __restrict__ gamma,
                          const u16* __restrict__ beta, u16* __restrict__ out,
                          const int* __restrict__ flag) {
  const size_t row = blockIdx.x;
  const int tid = threadIdx.x;
  const int f = flag ? *flag : 0;
  float v0, v1, v2, v3;
  if (f) {
    const float4 v = *((const float4*)x + row * 256 + tid);
    v0 = v.x; v1 = v.y; v2 = v.z; v3 = v.w;
  } else {
    const ushort4 u = *((const ushort4*)x + row * 256 + tid);
    v0 = bf2f(u.x); v1 = bf2f(u.y); v2 = bf2f(u.z); v3 = bf2f(u.w);
  }
  float s = v0 + v1 + v2 + v3;
  float sq = v0 * v0 + v1 * v1 + v2 * v2 + v3 * v3;
#pragma unroll
  for (int off = 32; off > 0; off >>= 1) {
    s += __shfl_down(s, off);
    sq += __shfl_down(sq, off);
  }
  __shared__ float ss[4], ssq[4];
  if ((tid & 63) == 0) { ss[tid >> 6] = s; ssq[tid >> 6] = sq; }
  __syncthreads();
  s = ss[0] + ss[1] + ss[2] + ss[3];
  sq = ssq[0] + ssq[1] + ssq[2] + ssq[3];
  const float mean = s * (1.f / 1024.f);
  const float var = (sq - 1024.f * mean * mean) * (1.f / 1023.f);
  const float rs = rsqrtf(var + 1e-5f);
  const ushort4 g = *(const ushort4*)&gamma[tid * 4];
  const ushort4 be = *(const ushort4*)&beta[tid * 4];
  ushort4 o;
  o.x = f2bf(bf2f(g.x) * (v0 - mean) * rs + bf2f(be.x));
  o.y = f2bf(bf2f(g.y) * (v1 - mean) * rs + bf2f(be.y));
  o.z = f2bf(bf2f(g.z) * (v2 - mean) * rs + bf2f(be.z));
  o.w = f2bf(bf2f(g.w) * (v3 - mean) * rs + bf2f(be.w));
  *(ushort4*)&out[row * 1024 + tid * 4] = o;
}

// WT[w*1024+h*64+e][d] = W_w[h][d][e]; coalesced 64x64 LDS tiles
__global__ void transpose_qkv2(const void* __restrict__ Wq, const void* __restrict__ Wk,
                               const void* __restrict__ Wv, u16* __restrict__ WT,
                               const int* __restrict__ flag) {
  __shared__ u16 tile[64][65];
  const int f = *flag;
  const int wh = blockIdx.y;
  const int w = wh >> 4, hh = wh & 15;
  const int tr = blockIdx.x * 64;
  const void* W = (w == 0) ? Wq : ((w == 1) ? Wk : Wv);
  const size_t hbase = (size_t)hh * 65536;
  const int lx = threadIdx.x & 63, ly = threadIdx.x >> 6;
#pragma unroll
  for (int i = 0; i < 16; i++)
    tile[ly * 16 + i][lx] = ld_cv(W, hbase + (size_t)(tr + ly * 16 + i) * 64 + lx, f);
  __syncthreads();
#pragma unroll
  for (int i = 0; i < 16; i++)
    WT[((size_t)(w * 1024 + hh * 64 + ly * 16 + i)) * 1024 + tr + lx] =
        tile[lx][ly * 16 + i];
}

// dst[c*R + r] = src[r*C + c]
__global__ void transpose_tile(const void* __restrict__ src, u16* __restrict__ dst,
                               int R, int C, const int* __restrict__ flag) {
  __shared__ u16 tile[64][65];
  const int f = *flag;
  const int tc = blockIdx.x * 64, tr = blockIdx.y * 64;
  const int lx = threadIdx.x & 63, ly = threadIdx.x >> 6;
#pragma unroll
  for (int i = 0; i < 16; i++)
    tile[ly * 16 + i][lx] = ld_cv(src, (size_t)(tr + ly * 16 + i) * C + tc + lx, f);
  __syncthreads();
#pragma unroll
  for (int i = 0; i < 16; i++)
    dst[(size_t)(tc + ly * 16 + i) * R + tr + lx] = tile[lx][ly * 16 + i];
}

// V [bh][t][64] -> Vt [bh][e][t]
__global__ void transpose_v(const u16* __restrict__ src, u16* __restrict__ dst) {
  __shared__ u16 tile[64][65];
  const int bh = blockIdx.y;
  const int tt = blockIdx.x * 64;
  const int lx = threadIdx.x & 63, ly = threadIdx.x >> 6;
#pragma unroll
  for (int i = 0; i < 16; i++)
    tile[ly * 16 + i][lx] = src[((size_t)bh * 2048 + tt + ly * 16 + i) * 64 + lx];
  __syncthreads();
#pragma unroll
  for (int i = 0; i < 16; i++)
    dst[((size_t)bh * 64 + ly * 16 + i) * 2048 + tt + lx] = tile[lx][ly * 16 + i];
}

extern "C" void kernel_launch(void* const* d_in, const int* in_sizes, int n_in,
                              void* d_out, int out_size, void* d_ws, size_t ws_size,
                              hipStream_t stream) {
  const void* x      = d_in[0];
  const void* Wq     = d_in[1];
  const void* Wk     = d_in[2];
  const void* Wv     = d_in[3];
  const void* W1     = d_in[4];
  const void* b1     = d_in[5];
  const void* W2     = d_in[6];
  const void* b2     = d_in[7];
  const void* gamma1 = d_in[8];
  const void* beta1  = d_in[9];
  const void* gamma2 = d_in[10];
  const void* beta2  = d_in[11];
  u16* ws = (u16*)d_ws;

  const size_t M4 = 4194304;
  u16* h   = ws;
  u16* Vtb = ws;
  u16* Qb  = ws + 1 * M4;
  u16* Kb  = ws + 2 * M4;
  u16* Vb  = ws + 3 * M4;
  u16* WTq = ws + 4 * M4;
  u16* x2  = ws + 4 * M4;
  u16* h2  = ws + 5 * M4;
  u16* W1T = ws + 6 * M4;
  u16* W2T = ws + 7 * M4;
  u16* ff1 = ws;
  u16* smallc = ws + 8 * M4;
  u16* b1c = smallc, *b2c = smallc + 4096, *g1c = smallc + 5120,
     *be1c = smallc + 6144, *g2c = smallc + 7168, *be2c = smallc + 8192;
  int* flag = (int*)(ws + 8 * M4 + 9216);

  sniff_kernel<<<1, 256, 0, stream>>>((const u16*)x, flag);
  conv_small<<<36, 256, 0, stream>>>(b1, b2, gamma1, beta1, gamma2, beta2,
                                     smallc, flag);
  transpose_qkv2<<<dim3(16, 48), 256, 0, stream>>>(Wq, Wk, Wv, WTq, flag);
  transpose_tile<<<dim3(64, 16), 256, 0, stream>>>(W1, W1T, 1024, 4096, flag);
  transpose_tile<<<dim3(16, 64), 256, 0, stream>>>(W2, W2T, 4096, 1024, flag);
  ln_kernel<<<4096, 256, 0, stream>>>(x, g1c, be1c, h, flag);
  gemm_bt<0, 2, 2><<<768, 256, 0, stream>>>(h, WTq, 1024, 24, 3072,
                                            nullptr, nullptr, nullptr,
                                            Qb, Kb, Vb, flag);
  transpose_v<<<dim3(32, 32), 256, 0, stream>>>(Vb, Vtb);
  attn_mfma<<<2048, 256, 0, stream>>>(Qb, Kb, Vtb, x, flag, x2);
  ln_kernel<<<4096, 256, 0, stream>>>(x2, g2c, be2c, h2, nullptr);
  gemm_bt<1, 2, 2><<<1024, 256, 0, stream>>>(h2, W1T, 1024, 32, 4096,
                                             b1c, nullptr, ff1,
                                             nullptr, nullptr, nullptr, flag);
  gemm_bt<2, 2, 1><<<512, 128, 0, stream>>>(ff1, W2T, 4096, 16, 1024,
                                            b2c, x2, d_out,
                                            nullptr, nullptr, nullptr, flag);
}

// Round 10
// 423.123 us; speedup vs baseline: 8.8441x; 1.0002x over previous
//
#include <hip/hip_runtime.h>

typedef unsigned short u16;
typedef __bf16 bf16;
typedef __attribute__((ext_vector_type(8))) __bf16 bf16x8;
typedef __attribute__((ext_vector_type(4))) float f32x4;
typedef __attribute__((ext_vector_type(8))) unsigned short u16x8;

__device__ __forceinline__ float bf2f(u16 h) {
  return __uint_as_float(((unsigned int)h) << 16);
}
__device__ __forceinline__ u16 f2bf(float f) {
  unsigned int u = __float_as_uint(f);
  return (u16)((u + 0x7fffu + ((u >> 16) & 1u)) >> 16);
}
__device__ __forceinline__ u16 ld_cv(const void* p, size_t i, int f32) {
  return f32 ? f2bf(((const float*)p)[i]) : ((const u16*)p)[i];
}
__device__ __forceinline__ float ld_f(const void* p, size_t i, int f32) {
  return f32 ? ((const float*)p)[i] : bf2f(((const u16*)p)[i]);
}
__device__ __forceinline__ void async16(const u16* g, u16* l) {
  __builtin_amdgcn_global_load_lds(
      (const __attribute__((address_space(1))) unsigned int*)g,
      (__attribute__((address_space(3))) unsigned int*)l, 16, 0, 0);
}
__device__ __forceinline__ unsigned pk_bf16(float hi, float lo) {
  return __builtin_amdgcn_perm(__float_as_uint(hi) + 0x8000u,
                               __float_as_uint(lo) + 0x8000u, 0x07060302u);
}

// ---- dtype sniffer ------------------------------------------------------
__global__ void sniff_kernel(const u16* __restrict__ x, int* __restrict__ flag) {
  const int tid = threadIdx.x;
  int me = 0;
#pragma unroll
  for (int j = 0; j < 4; j++) {
    const u16 v = x[(tid * 4 + j) * 2];
    const int e = (v >> 7) & 0xFF;
    me = me > e ? me : e;
  }
#pragma unroll
  for (int off = 32; off > 0; off >>= 1) {
    const int o = __shfl_down(me, off);
    me = me > o ? me : o;
  }
  __shared__ int sm[4];
  if ((tid & 63) == 0) sm[tid >> 6] = me;
  __syncthreads();
  if (tid == 0) {
    int a = sm[0] > sm[1] ? sm[0] : sm[1];
    int b = sm[2] > sm[3] ? sm[2] : sm[3];
    *flag = ((a > b ? a : b) >= 140) ? 1 : 0;
  }
}

// ---- mega-prep: all three weight transposes in one launch ----------------
// blocks [0,768): WTq; [768,1792): W1T; [1792,2816): W2T
__global__ void prep_kernel(const void* __restrict__ Wq, const void* __restrict__ Wk,
                            const void* __restrict__ Wv, const void* __restrict__ W1,
                            const void* __restrict__ W2,
                            u16* __restrict__ WTq, u16* __restrict__ W1T,
                            u16* __restrict__ W2T, const int* __restrict__ flag) {
  __shared__ u16 tile[64][65];
  const int f = *flag;
  const int bid = blockIdx.x;
  const int lx = threadIdx.x & 63, ly = threadIdx.x >> 6;
  if (bid < 768) {
    // WTq[w*1024+h*64+e][d] = W_w[h][d][e]
    const int bx = bid & 15, wh = bid >> 4;
    const int w = wh >> 4, hh = wh & 15;
    const int tr = bx * 64;
    const void* W = (w == 0) ? Wq : ((w == 1) ? Wk : Wv);
    const size_t hbase = (size_t)hh * 65536;
#pragma unroll
    for (int i = 0; i < 16; i++)
      tile[ly * 16 + i][lx] = ld_cv(W, hbase + (size_t)(tr + ly * 16 + i) * 64 + lx, f);
    __syncthreads();
#pragma unroll
    for (int i = 0; i < 16; i++)
      WTq[((size_t)(w * 1024 + hh * 64 + ly * 16 + i)) * 1024 + tr + lx] =
          tile[lx][ly * 16 + i];
  } else {
    // generic dst[c*R + r] = src[r*C + c]
    const void* src;
    u16* dst;
    int R, C, tc, tr;
    if (bid < 1792) {
      const int j = bid - 768;
      src = W1; dst = W1T; R = 1024; C = 4096;
      tc = (j & 63) * 64; tr = (j >> 6) * 64;
    } else {
      const int j = bid - 1792;
      src = W2; dst = W2T; R = 4096; C = 1024;
      tc = (j & 15) * 64; tr = (j >> 4) * 64;
    }
#pragma unroll
    for (int i = 0; i < 16; i++)
      tile[ly * 16 + i][lx] = ld_cv(src, (size_t)(tr + ly * 16 + i) * C + tc + lx, f);
    __syncthreads();
#pragma unroll
    for (int i = 0; i < 16; i++)
      dst[(size_t)(tc + ly * 16 + i) * R + tr + lx] = tile[lx][ly * 16 + i];
  }
}

// ---------------- GEMM: C[m][n] = sum_k A[m][k] * BT[n][k] ----------------
// Tile BM(=WR*64) x BN(=WC*64); BK=64 as two BK=32 half-tiles, one barrier
// pair, 32 MFMA/wave per drain. XCD-affine grid: MS=false -> xcd owns
// n-strip (NX = n-tile count); MS=true -> xcd owns m-strip (NX = m-tiles).
template <int EPI, int WR, int WC, bool MS>
__launch_bounds__(WR * WC * 64)
__global__ void gemm_bt(const u16* __restrict__ A, const u16* __restrict__ B,
                        int K, int NX, int N,
                        const void* __restrict__ bias, const u16* __restrict__ res,
                        void* __restrict__ out,
                        u16* __restrict__ Qo, u16* __restrict__ Ko, u16* __restrict__ Vo,
                        const int* __restrict__ flag) {
  constexpr int BM = WR * 64, BN = WC * 64, T = WR * WC * 64;
  constexpr int RPA = T / 4;
  constexpr int RAH = BM / RPA;
  constexpr int RBH = BN / RPA;
  __shared__ __align__(16) u16 As[BM * 64];
  __shared__ __align__(16) u16 Bs[BN * 64];
  const int tid = threadIdx.x;
  const int bid = blockIdx.x;
  const int sxp = NX >> 3;
  const int xcd = bid & 7, j9 = bid >> 3;
  int m0, n0;
  if (MS) {
    m0 = (xcd * sxp + j9 % sxp) * BM;
    n0 = (j9 / sxp) * BN;
  } else {
    n0 = (xcd * sxp + j9 % sxp) * BN;
    m0 = (j9 / sxp) * BM;
  }
  const int wave = tid >> 6, lane = tid & 63;
  const int wm = (wave / WC) * 64, wn = (wave % WC) * 64;
  const int lm = lane & 15, lq = lane >> 4;
  const int fb = (EPI >= 1) ? *flag : 0;

  const f32x4 zero = {0.f, 0.f, 0.f, 0.f};
  f32x4 acc[4][4];
#pragma unroll
  for (int i = 0; i < 4; i++)
#pragma unroll
    for (int j = 0; j < 4; j++) acc[i][j] = zero;

  const int ar = tid >> 2;
  const int ac = (tid & 3) * 8;
  const u16* Ag = A + (size_t)(m0 + ar) * K + ac;
  const u16* Bg = B + (size_t)(n0 + ar) * K + ac;
  u16* AsP = &As[tid * 8];
  u16* BsP = &Bs[tid * 8];

  for (int k0 = 0; k0 < K; k0 += 64) {
#pragma unroll
    for (int hh = 0; hh < 2; hh++) {
#pragma unroll
      for (int c = 0; c < RAH; c++)
        async16(Ag + k0 + hh * 32 + (size_t)c * RPA * K,
                AsP + hh * BM * 32 + c * RPA * 32);
#pragma unroll
      for (int c = 0; c < RBH; c++)
        async16(Bg + k0 + hh * 32 + (size_t)c * RPA * K,
                BsP + hh * BN * 32 + c * RPA * 32);
    }
    __syncthreads();  // drains vmcnt(0): both k-halves ready
    bf16x8 a0[4], a1[4], b0[4], b1[4];
#pragma unroll
    for (int i = 0; i < 4; i++) {
      a0[i] = *(const bf16x8*)&As[(wm + i * 16 + lm) * 32 + lq * 8];
      a1[i] = *(const bf16x8*)&As[BM * 32 + (wm + i * 16 + lm) * 32 + lq * 8];
    }
#pragma unroll
    for (int i = 0; i < 4; i++) {
      b0[i] = *(const bf16x8*)&Bs[(wn + i * 16 + lm) * 32 + lq * 8];
      b1[i] = *(const bf16x8*)&Bs[BN * 32 + (wn + i * 16 + lm) * 32 + lq * 8];
    }
#pragma unroll
    for (int i = 0; i < 4; i++)
#pragma unroll
      for (int j = 0; j < 4; j++) {
        acc[i][j] = __builtin_amdgcn_mfma_f32_16x16x32_bf16(a0[i], b0[j], acc[i][j], 0, 0, 0);
        acc[i][j] = __builtin_amdgcn_mfma_f32_16x16x32_bf16(a1[i], b1[j], acc[i][j], 0, 0, 0);
      }
    __syncthreads();
  }

#pragma unroll
  for (int i = 0; i < 4; i++) {
#pragma unroll
    for (int r = 0; r < 4; r++) {
      const int row = m0 + wm + i * 16 + lq * 4 + r;
#pragma unroll
      for (int j = 0; j < 4; j++) {
        const int col = n0 + wn + j * 16 + lm;
        const float c = acc[i][j][r];
        if (EPI == 0) {
          const int bb = row >> 11, t = row & 2047;
          const int w = col >> 10, nn = col & 1023;
          const int hh = nn >> 6, e = nn & 63;
          u16* dst = (w == 0) ? Qo : ((w == 1) ? Ko : Vo);
          dst[(((size_t)(bb * 16 + hh)) * 2048 + t) * 64 + e] = f2bf(c);
        } else if (EPI == 1) {
          const float v = c + ld_f(bias, col, fb);
          ((u16*)out)[(size_t)row * N + col] = f2bf(v > 0.f ? v : 0.f);
        } else {
          const float v = c + ld_f(bias, col, fb) + bf2f(res[(size_t)row * N + col]);
          if (fb)
            ((float*)out)[(size_t)row * N + col] = v;
          else
            ((u16*)out)[(size_t)row * N + col] = f2bf(v);
        }
      }
    }
  }
}

// ---------------- MFMA flash attention: split-K + XCD affinity -------------
__launch_bounds__(256)
__global__ void attn_mfma(const u16* __restrict__ Q, const u16* __restrict__ K,
                          const u16* __restrict__ Vt, const void* __restrict__ xres,
                          const int* __restrict__ flag, u16* __restrict__ x2) {
  __shared__ __align__(16) float Olds[4][32][68];
  __shared__ float Llds[4][2][16];
  const int tid = threadIdx.x;
  const int wave = tid >> 6, lane = tid & 63;
  const int lm = lane & 15, quad = lane >> 4;
  const int bid = blockIdx.x;
  const int xcd = bid & 7, jj = bid >> 3;
  const int bh = xcd + 8 * (jj & 3);
  const int qb = 63 - (jj >> 2);
  const int qw0 = qb * 32;
  const int b = bh >> 4, h = bh & 15;

  bf16x8 qf[2][2];
#pragma unroll
  for (int s = 0; s < 2; s++) {
    const u16* Qp = Q + ((size_t)bh * 2048 + qw0 + s * 16 + lm) * 64 + quad * 8;
    qf[s][0] = *(const bf16x8*)Qp;
    qf[s][1] = *(const bf16x8*)(Qp + 32);
  }
  const f32x4 zero = {0.f, 0.f, 0.f, 0.f};
  f32x4 ot[2][4];
#pragma unroll
  for (int s = 0; s < 2; s++)
#pragma unroll
    for (int j = 0; j < 4; j++) ot[s][j] = zero;
  float l[2] = {0.f, 0.f};

  const u16* Kbh = K + (size_t)bh * 131072;
  const u16* Vbh = Vt + (size_t)bh * 131072;
  const int nt = qb + 1;
  const int cw = (nt + 3) >> 2;
  const int t0 = wave * cw;
  const int t1e = t0 + cw;
  const int t1 = (t1e < nt) ? t1e : nt;

  union V8 { bf16x8 v; struct { unsigned long long lo, hi; } q; };
  bf16x8 kfA[2][2], kfB[2][2];
  V8 vfA[4], vfB[4];

  auto loadKV = [&](int ks, bf16x8 (&kfd)[2][2], V8 (&vfd)[4]) {
#pragma unroll
    for (int hh = 0; hh < 2; hh++) {
      const u16* Kp = Kbh + (size_t)(ks + hh * 16 + lm) * 64 + quad * 8;
      kfd[hh][0] = *(const bf16x8*)Kp;
      kfd[hh][1] = *(const bf16x8*)(Kp + 32);
    }
#pragma unroll
    for (int j = 0; j < 4; j++) {
      const u16* Vp = Vbh + (size_t)(j * 16 + lm) * 2048 + ks + quad * 4;
      vfd[j].q.lo = *(const unsigned long long*)Vp;
      vfd[j].q.hi = *(const unsigned long long*)(Vp + 16);
    }
  };

  auto computeTile = [&](int t, const bf16x8 (&kfc)[2][2], const V8 (&vfc)[4]) {
    f32x4 S[2][2];
#pragma unroll
    for (int s = 0; s < 2; s++)
#pragma unroll
      for (int hh = 0; hh < 2; hh++) {
        f32x4 a = zero;
        a = __builtin_amdgcn_mfma_f32_16x16x32_bf16(kfc[hh][0], qf[s][0], a, 0, 0, 0);
        a = __builtin_amdgcn_mfma_f32_16x16x32_bf16(kfc[hh][1], qf[s][1], a, 0, 0, 0);
        S[s][hh] = a;
      }
    const bool maskT = (t == qb);
#pragma unroll
    for (int s = 0; s < 2; s++) {
      float p[2][4];
#pragma unroll
      for (int hh = 0; hh < 2; hh++)
#pragma unroll
        for (int r = 0; r < 4; r++) {
          float v = __expf(S[s][hh][r] * 0.03125f);
          if (maskT && (hh * 16 + quad * 4 + r > s * 16 + lm)) v = 0.f;
          l[s] += v;
          p[hh][r] = v;
        }
      unsigned pk[4];
      pk[0] = pk_bf16(p[0][1], p[0][0]);
      pk[1] = pk_bf16(p[0][3], p[0][2]);
      pk[2] = pk_bf16(p[1][1], p[1][0]);
      pk[3] = pk_bf16(p[1][3], p[1][2]);
      const bf16x8 pf = *(const bf16x8*)pk;
#pragma unroll
      for (int j = 0; j < 4; j++)
        ot[s][j] = __builtin_amdgcn_mfma_f32_16x16x32_bf16(vfc[j].v, pf, ot[s][j], 0, 0, 0);
    }
  };

  if (t0 < t1) {
    loadKV(t0 * 32, kfA, vfA);
    for (int t = t0; t < t1; t += 2) {
      if (t + 1 < t1) loadKV((t + 1) * 32, kfB, vfB);
      computeTile(t, kfA, vfA);
      if (t + 1 >= t1) break;
      if (t + 2 < t1) loadKV((t + 2) * 32, kfA, vfA);
      computeTile(t + 1, kfB, vfB);
    }
  }

#pragma unroll
  for (int s = 0; s < 2; s++) {
    l[s] += __shfl_xor(l[s], 16);
    l[s] += __shfl_xor(l[s], 32);
  }

#pragma unroll
  for (int s = 0; s < 2; s++)
#pragma unroll
    for (int j = 0; j < 4; j++)
      *(f32x4*)&Olds[wave][s * 16 + lm][j * 16 + quad * 4] = ot[s][j];
  if (quad == 0) {
    Llds[wave][0][lm] = l[0];
    Llds[wave][1][lm] = l[1];
  }
  __syncthreads();

  const int q = tid >> 3;
  const int e0 = (tid & 7) * 8;
  f32x4 oa = zero, ob = zero;
#pragma unroll
  for (int w = 0; w < 4; w++) {
    oa += *(const f32x4*)&Olds[w][q][e0];
    ob += *(const f32x4*)&Olds[w][q][e0 + 4];
  }
  const float lt = Llds[0][q >> 4][q & 15] + Llds[1][q >> 4][q & 15] +
                   Llds[2][q >> 4][q & 15] + Llds[3][q >> 4][q & 15];
  const float linv = 1.f / lt;
  const size_t rowbase = ((size_t)(b * 2048 + qw0 + q)) * 1024 + h * 64 + e0;
  float xv[8];
  if (*flag) {
    const float* xf = (const float*)xres + rowbase;
    const float4 u0 = *(const float4*)xf;
    const float4 u1 = *(const float4*)(xf + 4);
    xv[0] = u0.x; xv[1] = u0.y; xv[2] = u0.z; xv[3] = u0.w;
    xv[4] = u1.x; xv[5] = u1.y; xv[6] = u1.z; xv[7] = u1.w;
  } else {
    const u16x8 u = *(const u16x8*)((const u16*)xres + rowbase);
#pragma unroll
    for (int k = 0; k < 8; k++) xv[k] = bf2f(u[k]);
  }
  u16x8 o8;
#pragma unroll
  for (int k = 0; k < 4; k++) o8[k] = f2bf(xv[k] + oa[k] * linv);
#pragma unroll
  for (int k = 0; k < 4; k++) o8[4 + k] = f2bf(xv[4 + k] + ob[k] * linv);
  *(u16x8*)&x2[rowbase] = o8;
}

// ---------------- LayerNorm (ddof=1, eps=1e-5), raw dual-dtype inputs ------
__launch_bounds__(256)
__global__ void ln_kernel(const void* __restrict__ x, const void* __restrict__ gamma,
                          const void* __restrict__ beta, u16* __restrict__ out,
                          const int* __restrict__ flag, int xraw) {
  const size_t row = blockIdx.x;
  const int tid = threadIdx.x;
  const int f = *flag;
  const int fx = xraw ? f : 0;
  float v0, v1, v2, v3;
  if (fx) {
    const float4 v = *((const float4*)x + row * 256 + tid);
    v0 = v.x; v1 = v.y; v2 = v.z; v3 = v.w;
  } else {
    const ushort4 u = *((const ushort4*)x + row * 256 + tid);
    v0 = bf2f(u.x); v1 = bf2f(u.y); v2 = bf2f(u.z); v3 = bf2f(u.w);
  }
  float s = v0 + v1 + v2 + v3;
  float sq = v0 * v0 + v1 * v1 + v2 * v2 + v3 * v3;
#pragma unroll
  for (int off = 32; off > 0; off >>= 1) {
    s += __shfl_down(s, off);
    sq += __shfl_down(sq, off);
  }
  __shared__ float ss[4], ssq[4];
  if ((tid & 63) == 0) { ss[tid >> 6] = s; ssq[tid >> 6] = sq; }
  __syncthreads();
  s = ss[0] + ss[1] + ss[2] + ss[3];
  sq = ssq[0] + ssq[1] + ssq[2] + ssq[3];
  const float mean = s * (1.f / 1024.f);
  const float var = (sq - 1024.f * mean * mean) * (1.f / 1023.f);
  const float rs = rsqrtf(var + 1e-5f);
  const int c0 = tid * 4;
  ushort4 o;
  o.x = f2bf(ld_f(gamma, c0 + 0, f) * (v0 - mean) * rs + ld_f(beta, c0 + 0, f));
  o.y = f2bf(ld_f(gamma, c0 + 1, f) * (v1 - mean) * rs + ld_f(beta, c0 + 1, f));
  o.z = f2bf(ld_f(gamma, c0 + 2, f) * (v2 - mean) * rs + ld_f(beta, c0 + 2, f));
  o.w = f2bf(ld_f(gamma, c0 + 3, f) * (v3 - mean) * rs + ld_f(beta, c0 + 3, f));
  *(ushort4*)&out[row * 1024 + tid * 4] = o;
}

// V [bh][t][64] -> Vt [bh][e][t]
__global__ void transpose_v(const u16* __restrict__ src, u16* __restrict__ dst) {
  __shared__ u16 tile[64][65];
  const int bh = blockIdx.y;
  const int tt = blockIdx.x * 64;
  const int lx = threadIdx.x & 63, ly = threadIdx.x >> 6;
#pragma unroll
  for (int i = 0; i < 16; i++)
    tile[ly * 16 + i][lx] = src[((size_t)bh * 2048 + tt + ly * 16 + i) * 64 + lx];
  __syncthreads();
#pragma unroll
  for (int i = 0; i < 16; i++)
    dst[((size_t)bh * 64 + ly * 16 + i) * 2048 + tt + lx] = tile[lx][ly * 16 + i];
}

extern "C" void kernel_launch(void* const* d_in, const int* in_sizes, int n_in,
                              void* d_out, int out_size, void* d_ws, size_t ws_size,
                              hipStream_t stream) {
  const void* x      = d_in[0];
  const void* Wq     = d_in[1];
  const void* Wk     = d_in[2];
  const void* Wv     = d_in[3];
  const void* W1     = d_in[4];
  const void* b1     = d_in[5];
  const void* W2     = d_in[6];
  const void* b2     = d_in[7];
  const void* gamma1 = d_in[8];
  const void* beta1  = d_in[9];
  const void* gamma2 = d_in[10];
  const void* beta2  = d_in[11];
  u16* ws = (u16*)d_ws;

  const size_t M4 = 4194304;
  u16* h   = ws;
  u16* Vtb = ws;
  u16* Qb  = ws + 1 * M4;
  u16* Kb  = ws + 2 * M4;
  u16* Vb  = ws + 3 * M4;
  u16* WTq = ws + 4 * M4;
  u16* x2  = ws + 4 * M4;
  u16* h2  = ws + 5 * M4;
  u16* W1T = ws + 6 * M4;
  u16* W2T = ws + 7 * M4;
  u16* ff1 = ws;
  int* flag = (int*)(ws + 8 * M4 + 9216);

  sniff_kernel<<<1, 256, 0, stream>>>((const u16*)x, flag);
  prep_kernel<<<2816, 256, 0, stream>>>(Wq, Wk, Wv, W1, W2, WTq, W1T, W2T, flag);
  ln_kernel<<<4096, 256, 0, stream>>>(x, gamma1, beta1, h, flag, 1);
  gemm_bt<0, 2, 2, false><<<768, 256, 0, stream>>>(h, WTq, 1024, 24, 3072,
                                                   nullptr, nullptr, nullptr,
                                                   Qb, Kb, Vb, flag);
  transpose_v<<<dim3(32, 32), 256, 0, stream>>>(Vb, Vtb);
  attn_mfma<<<2048, 256, 0, stream>>>(Qb, Kb, Vtb, x, flag, x2);
  ln_kernel<<<4096, 256, 0, stream>>>(x2, gamma2, beta2, h2, flag, 0);
  gemm_bt<1, 2, 2, false><<<1024, 256, 0, stream>>>(h2, W1T, 1024, 32, 4096,
                                                    b1, nullptr, ff1,
                                                    nullptr, nullptr, nullptr, flag);
  gemm_bt<2, 2, 1, true><<<512, 128, 0, stream>>>(ff1, W2T, 4096, 32, 1024,
                                                  b2, x2, d_out,
                                                  nullptr, nullptr, nullptr, flag);
}

// Round 11
// 418.261 us; speedup vs baseline: 8.9470x; 1.0116x over previous
//
#include <hip/hip_runtime.h>

typedef unsigned short u16;
typedef __bf16 bf16;
typedef __attribute__((ext_vector_type(8))) __bf16 bf16x8;
typedef __attribute__((ext_vector_type(4))) float f32x4;
typedef __attribute__((ext_vector_type(8))) unsigned short u16x8;

__device__ __forceinline__ float bf2f(u16 h) {
  return __uint_as_float(((unsigned int)h) << 16);
}
__device__ __forceinline__ u16 f2bf(float f) {
  unsigned int u = __float_as_uint(f);
  return (u16)((u + 0x7fffu + ((u >> 16) & 1u)) >> 16);
}
__device__ __forceinline__ u16 ld_cv(const void* p, size_t i, int f32) {
  return f32 ? f2bf(((const float*)p)[i]) : ((const u16*)p)[i];
}
__device__ __forceinline__ float ld_f(const void* p, size_t i, int f32) {
  return f32 ? ((const float*)p)[i] : bf2f(((const u16*)p)[i]);
}
__device__ __forceinline__ void async16(const u16* g, u16* l) {
  __builtin_amdgcn_global_load_lds(
      (const __attribute__((address_space(1))) unsigned int*)g,
      (__attribute__((address_space(3))) unsigned int*)l, 16, 0, 0);
}
__device__ __forceinline__ unsigned pk_bf16(float hi, float lo) {
  return __builtin_amdgcn_perm(__float_as_uint(hi) + 0x8000u,
                               __float_as_uint(lo) + 0x8000u, 0x07060302u);
}

// ---- dtype sniffer ------------------------------------------------------
__global__ void sniff_kernel(const u16* __restrict__ x, int* __restrict__ flag) {
  const int tid = threadIdx.x;
  int me = 0;
#pragma unroll
  for (int j = 0; j < 4; j++) {
    const u16 v = x[(tid * 4 + j) * 2];
    const int e = (v >> 7) & 0xFF;
    me = me > e ? me : e;
  }
#pragma unroll
  for (int off = 32; off > 0; off >>= 1) {
    const int o = __shfl_down(me, off);
    me = me > o ? me : o;
  }
  __shared__ int sm[4];
  if ((tid & 63) == 0) sm[tid >> 6] = me;
  __syncthreads();
  if (tid == 0) {
    int a = sm[0] > sm[1] ? sm[0] : sm[1];
    int b = sm[2] > sm[3] ? sm[2] : sm[3];
    *flag = ((a > b ? a : b) >= 140) ? 1 : 0;
  }
}

// ---- mega-prep: all three weight transposes in one launch ----------------
__global__ void prep_kernel(const void* __restrict__ Wq, const void* __restrict__ Wk,
                            const void* __restrict__ Wv, const void* __restrict__ W1,
                            const void* __restrict__ W2,
                            u16* __restrict__ WTq, u16* __restrict__ W1T,
                            u16* __restrict__ W2T, const int* __restrict__ flag) {
  __shared__ u16 tile[64][65];
  const int f = *flag;
  const int bid = blockIdx.x;
  const int lx = threadIdx.x & 63, ly = threadIdx.x >> 6;
  if (bid < 768) {
    const int bx = bid & 15, wh = bid >> 4;
    const int w = wh >> 4, hh = wh & 15;
    const int tr = bx * 64;
    const void* W = (w == 0) ? Wq : ((w == 1) ? Wk : Wv);
    const size_t hbase = (size_t)hh * 65536;
#pragma unroll
    for (int i = 0; i < 16; i++)
      tile[ly * 16 + i][lx] = ld_cv(W, hbase + (size_t)(tr + ly * 16 + i) * 64 + lx, f);
    __syncthreads();
#pragma unroll
    for (int i = 0; i < 16; i++)
      WTq[((size_t)(w * 1024 + hh * 64 + ly * 16 + i)) * 1024 + tr + lx] =
          tile[lx][ly * 16 + i];
  } else {
    const void* src;
    u16* dst;
    int R, C, tc, tr;
    if (bid < 1792) {
      const int j = bid - 768;
      src = W1; dst = W1T; R = 1024; C = 4096;
      tc = (j & 63) * 64; tr = (j >> 6) * 64;
    } else {
      const int j = bid - 1792;
      src = W2; dst = W2T; R = 4096; C = 1024;
      tc = (j & 15) * 64; tr = (j >> 4) * 64;
    }
#pragma unroll
    for (int i = 0; i < 16; i++)
      tile[ly * 16 + i][lx] = ld_cv(src, (size_t)(tr + ly * 16 + i) * C + tc + lx, f);
    __syncthreads();
#pragma unroll
    for (int i = 0; i < 16; i++)
      dst[(size_t)(tc + ly * 16 + i) * R + tr + lx] = tile[lx][ly * 16 + i];
  }
}

// ---------------- GEMM: C[m][n] = sum_k A[m][k] * BT[n][k] ----------------
// EPI 0 now writes V DIRECTLY TRANSPOSED into Vt[bh][e][t] (ushort4 over r).
template <int EPI, int WR, int WC, bool MS>
__launch_bounds__(WR * WC * 64)
__global__ void gemm_bt(const u16* __restrict__ A, const u16* __restrict__ B,
                        int K, int NX, int N,
                        const void* __restrict__ bias, const u16* __restrict__ res,
                        void* __restrict__ out,
                        u16* __restrict__ Qo, u16* __restrict__ Ko, u16* __restrict__ Vto,
                        const int* __restrict__ flag) {
  constexpr int BM = WR * 64, BN = WC * 64, T = WR * WC * 64;
  constexpr int RPA = T / 4;
  constexpr int RAH = BM / RPA;
  constexpr int RBH = BN / RPA;
  __shared__ __align__(16) u16 As[BM * 64];
  __shared__ __align__(16) u16 Bs[BN * 64];
  const int tid = threadIdx.x;
  const int bid = blockIdx.x;
  const int sxp = NX >> 3;
  const int xcd = bid & 7, j9 = bid >> 3;
  int m0, n0;
  if (MS) {
    m0 = (xcd * sxp + j9 % sxp) * BM;
    n0 = (j9 / sxp) * BN;
  } else {
    n0 = (xcd * sxp + j9 % sxp) * BN;
    m0 = (j9 / sxp) * BM;
  }
  const int wave = tid >> 6, lane = tid & 63;
  const int wm = (wave / WC) * 64, wn = (wave % WC) * 64;
  const int lm = lane & 15, lq = lane >> 4;
  const int fb = (EPI >= 1) ? *flag : 0;

  const f32x4 zero = {0.f, 0.f, 0.f, 0.f};
  f32x4 acc[4][4];
#pragma unroll
  for (int i = 0; i < 4; i++)
#pragma unroll
    for (int j = 0; j < 4; j++) acc[i][j] = zero;

  const int ar = tid >> 2;
  const int ac = (tid & 3) * 8;
  const u16* Ag = A + (size_t)(m0 + ar) * K + ac;
  const u16* Bg = B + (size_t)(n0 + ar) * K + ac;
  u16* AsP = &As[tid * 8];
  u16* BsP = &Bs[tid * 8];

  for (int k0 = 0; k0 < K; k0 += 64) {
#pragma unroll
    for (int hh = 0; hh < 2; hh++) {
#pragma unroll
      for (int c = 0; c < RAH; c++)
        async16(Ag + k0 + hh * 32 + (size_t)c * RPA * K,
                AsP + hh * BM * 32 + c * RPA * 32);
#pragma unroll
      for (int c = 0; c < RBH; c++)
        async16(Bg + k0 + hh * 32 + (size_t)c * RPA * K,
                BsP + hh * BN * 32 + c * RPA * 32);
    }
    __syncthreads();
    bf16x8 a0[4], a1[4], b0[4], b1[4];
#pragma unroll
    for (int i = 0; i < 4; i++) {
      a0[i] = *(const bf16x8*)&As[(wm + i * 16 + lm) * 32 + lq * 8];
      a1[i] = *(const bf16x8*)&As[BM * 32 + (wm + i * 16 + lm) * 32 + lq * 8];
    }
#pragma unroll
    for (int i = 0; i < 4; i++) {
      b0[i] = *(const bf16x8*)&Bs[(wn + i * 16 + lm) * 32 + lq * 8];
      b1[i] = *(const bf16x8*)&Bs[BN * 32 + (wn + i * 16 + lm) * 32 + lq * 8];
    }
#pragma unroll
    for (int i = 0; i < 4; i++)
#pragma unroll
      for (int j = 0; j < 4; j++) {
        acc[i][j] = __builtin_amdgcn_mfma_f32_16x16x32_bf16(a0[i], b0[j], acc[i][j], 0, 0, 0);
        acc[i][j] = __builtin_amdgcn_mfma_f32_16x16x32_bf16(a1[i], b1[j], acc[i][j], 0, 0, 0);
      }
    __syncthreads();
  }

  if (EPI == 0) {
#pragma unroll
    for (int i = 0; i < 4; i++) {
      const int row0 = m0 + wm + i * 16 + lq * 4;
      const int bb = row0 >> 11, t0 = row0 & 2047;
#pragma unroll
      for (int j = 0; j < 4; j++) {
        const int col = n0 + wn + j * 16 + lm;
        const int w = col >> 10, nn = col & 1023;
        const int hh = nn >> 6, e = nn & 63;
        if (w == 2) {
          ushort4 v4;
          v4.x = f2bf(acc[i][j][0]);
          v4.y = f2bf(acc[i][j][1]);
          v4.z = f2bf(acc[i][j][2]);
          v4.w = f2bf(acc[i][j][3]);
          *(ushort4*)&Vto[(((size_t)(bb * 16 + hh)) * 64 + e) * 2048 + t0] = v4;
        } else {
          u16* dst = (w == 0) ? Qo : Ko;
#pragma unroll
          for (int r = 0; r < 4; r++)
            dst[(((size_t)(bb * 16 + hh)) * 2048 + t0 + r) * 64 + e] =
                f2bf(acc[i][j][r]);
        }
      }
    }
  } else {
#pragma unroll
    for (int i = 0; i < 4; i++) {
#pragma unroll
      for (int r = 0; r < 4; r++) {
        const int row = m0 + wm + i * 16 + lq * 4 + r;
#pragma unroll
        for (int j = 0; j < 4; j++) {
          const int col = n0 + wn + j * 16 + lm;
          const float c = acc[i][j][r];
          if (EPI == 1) {
            const float v = c + ld_f(bias, col, fb);
            ((u16*)out)[(size_t)row * N + col] = f2bf(v > 0.f ? v : 0.f);
          } else {
            const float v = c + ld_f(bias, col, fb) + bf2f(res[(size_t)row * N + col]);
            if (fb)
              ((float*)out)[(size_t)row * N + col] = v;
            else
              ((u16*)out)[(size_t)row * N + col] = f2bf(v);
          }
        }
      }
    }
  }
}

// ---------------- MFMA flash attention v7: triangle-paired, balanced -------
// Block = (bh, pair): q-blocks qbA=pair, qbB=63-pair => exactly 65 tiles.
// 4 waves split the concatenated tile list; dual static state per wave.
// Single K/V register buffer (TLP hides latency). Two LDS merges.
__launch_bounds__(256)
__global__ void attn_mfma(const u16* __restrict__ Q, const u16* __restrict__ K,
                          const u16* __restrict__ Vt, const void* __restrict__ xres,
                          const int* __restrict__ flag, u16* __restrict__ x2) {
  __shared__ __align__(16) float Olds[4][32][68];
  __shared__ float Llds[4][2][16];
  const int tid = threadIdx.x;
  const int wave = tid >> 6, lane = tid & 63;
  const int lm = lane & 15, quad = lane >> 4;
  const int bid = blockIdx.x;
  const int xcd = bid & 7, jj = bid >> 3;
  const int bh = xcd + 8 * (jj & 3);
  const int pair = jj >> 2;            // 0..31
  const int qbA = pair, qbB = 63 - pair;
  const int b = bh >> 4, h = bh & 15;
  const int f32in = *flag;

  bf16x8 qfA[2][2], qfB[2][2];
#pragma unroll
  for (int s = 0; s < 2; s++) {
    const u16* QpA = Q + ((size_t)bh * 2048 + qbA * 32 + s * 16 + lm) * 64 + quad * 8;
    qfA[s][0] = *(const bf16x8*)QpA;
    qfA[s][1] = *(const bf16x8*)(QpA + 32);
    const u16* QpB = Q + ((size_t)bh * 2048 + qbB * 32 + s * 16 + lm) * 64 + quad * 8;
    qfB[s][0] = *(const bf16x8*)QpB;
    qfB[s][1] = *(const bf16x8*)(QpB + 32);
  }
  const f32x4 zero = {0.f, 0.f, 0.f, 0.f};
  f32x4 otA[2][4], otB[2][4];
#pragma unroll
  for (int s = 0; s < 2; s++)
#pragma unroll
    for (int j = 0; j < 4; j++) { otA[s][j] = zero; otB[s][j] = zero; }
  float lA[2] = {0.f, 0.f}, lB[2] = {0.f, 0.f};

  const u16* Kbh = K + (size_t)bh * 131072;
  const u16* Vbh = Vt + (size_t)bh * 131072;

  union V8 { bf16x8 v; struct { unsigned long long lo, hi; } q; };
  bf16x8 kf[2][2];
  V8 vf[4];

  auto loadKV = [&](int ks) {
#pragma unroll
    for (int hh = 0; hh < 2; hh++) {
      const u16* Kp = Kbh + (size_t)(ks + hh * 16 + lm) * 64 + quad * 8;
      kf[hh][0] = *(const bf16x8*)Kp;
      kf[hh][1] = *(const bf16x8*)(Kp + 32);
    }
#pragma unroll
    for (int j = 0; j < 4; j++) {
      const u16* Vp = Vbh + (size_t)(j * 16 + lm) * 2048 + ks + quad * 4;
      vf[j].q.lo = *(const unsigned long long*)Vp;
      vf[j].q.hi = *(const unsigned long long*)(Vp + 16);
    }
  };

  auto computeTile = [&](bool maskT, const bf16x8 (&qf)[2][2],
                         f32x4 (&ot)[2][4], float (&l)[2]) {
    f32x4 S[2][2];
#pragma unroll
    for (int s = 0; s < 2; s++)
#pragma unroll
      for (int hh = 0; hh < 2; hh++) {
        f32x4 a = zero;
        a = __builtin_amdgcn_mfma_f32_16x16x32_bf16(kf[hh][0], qf[s][0], a, 0, 0, 0);
        a = __builtin_amdgcn_mfma_f32_16x16x32_bf16(kf[hh][1], qf[s][1], a, 0, 0, 0);
        S[s][hh] = a;
      }
#pragma unroll
    for (int s = 0; s < 2; s++) {
      float p[2][4];
#pragma unroll
      for (int hh = 0; hh < 2; hh++)
#pragma unroll
        for (int r = 0; r < 4; r++) {
          float v = __expf(S[s][hh][r] * 0.03125f);
          if (maskT && (hh * 16 + quad * 4 + r > s * 16 + lm)) v = 0.f;
          l[s] += v;
          p[hh][r] = v;
        }
      unsigned pk[4];
      pk[0] = pk_bf16(p[0][1], p[0][0]);
      pk[1] = pk_bf16(p[0][3], p[0][2]);
      pk[2] = pk_bf16(p[1][1], p[1][0]);
      pk[3] = pk_bf16(p[1][3], p[1][2]);
      const bf16x8 pf = *(const bf16x8*)pk;
#pragma unroll
      for (int j = 0; j < 4; j++)
        ot[s][j] = __builtin_amdgcn_mfma_f32_16x16x32_bf16(vf[j].v, pf, ot[s][j], 0, 0, 0);
    }
  };

  // wave's slice of the 65-tile concatenated list (16/16/16/17)
  const int si = (65 * wave) >> 2;
  const int ei = (65 * (wave + 1)) >> 2;
  for (int i = si; i < ei; i++) {
    const bool isA = (i <= qbA);
    const int kt = isA ? i : (i - qbA - 1);
    loadKV(kt * 32);
    if (isA)
      computeTile(kt == qbA, qfA, otA, lA);
    else
      computeTile(kt == qbB, qfB, otB, lB);
  }

#pragma unroll
  for (int s = 0; s < 2; s++) {
    lA[s] += __shfl_xor(lA[s], 16);
    lA[s] += __shfl_xor(lA[s], 32);
    lB[s] += __shfl_xor(lB[s], 16);
    lB[s] += __shfl_xor(lB[s], 32);
  }

  auto mergeOut = [&](const f32x4 (&ot)[2][4], const float (&l)[2], int qw0) {
#pragma unroll
    for (int s = 0; s < 2; s++)
#pragma unroll
      for (int j = 0; j < 4; j++)
        *(f32x4*)&Olds[wave][s * 16 + lm][j * 16 + quad * 4] = ot[s][j];
    if (quad == 0) {
      Llds[wave][0][lm] = l[0];
      Llds[wave][1][lm] = l[1];
    }
    __syncthreads();
    const int q = tid >> 3;
    const int e0 = (tid & 7) * 8;
    f32x4 oa = zero, ob = zero;
#pragma unroll
    for (int w = 0; w < 4; w++) {
      oa += *(const f32x4*)&Olds[w][q][e0];
      ob += *(const f32x4*)&Olds[w][q][e0 + 4];
    }
    const float lt = Llds[0][q >> 4][q & 15] + Llds[1][q >> 4][q & 15] +
                     Llds[2][q >> 4][q & 15] + Llds[3][q >> 4][q & 15];
    const float linv = 1.f / lt;
    const size_t rowbase = ((size_t)(b * 2048 + qw0 + q)) * 1024 + h * 64 + e0;
    float xv[8];
    if (f32in) {
      const float* xf = (const float*)xres + rowbase;
      const float4 u0 = *(const float4*)xf;
      const float4 u1 = *(const float4*)(xf + 4);
      xv[0] = u0.x; xv[1] = u0.y; xv[2] = u0.z; xv[3] = u0.w;
      xv[4] = u1.x; xv[5] = u1.y; xv[6] = u1.z; xv[7] = u1.w;
    } else {
      const u16x8 u = *(const u16x8*)((const u16*)xres + rowbase);
#pragma unroll
      for (int k = 0; k < 8; k++) xv[k] = bf2f(u[k]);
    }
    u16x8 o8;
#pragma unroll
    for (int k = 0; k < 4; k++) o8[k] = f2bf(xv[k] + oa[k] * linv);
#pragma unroll
    for (int k = 0; k < 4; k++) o8[4 + k] = f2bf(xv[4 + k] + ob[k] * linv);
    *(u16x8*)&x2[rowbase] = o8;
    __syncthreads();  // Olds reads done before next merge's writes
  };

  mergeOut(otA, lA, qbA * 32);
  mergeOut(otB, lB, qbB * 32);
}

// ---------------- LayerNorm (ddof=1, eps=1e-5), raw dual-dtype inputs ------
__launch_bounds__(256)
__global__ void ln_kernel(const void* __restrict__ x, const void* __restrict__ gamma,
                          const void* __restrict__ beta, u16* __restrict__ out,
                          const int* __restrict__ flag, int xraw) {
  const size_t row = blockIdx.x;
  const int tid = threadIdx.x;
  const int f = *flag;
  const int fx = xraw ? f : 0;
  float v0, v1, v2, v3;
  if (fx) {
    const float4 v = *((const float4*)x + row * 256 + tid);
    v0 = v.x; v1 = v.y; v2 = v.z; v3 = v.w;
  } else {
    const ushort4 u = *((const ushort4*)x + row * 256 + tid);
    v0 = bf2f(u.x); v1 = bf2f(u.y); v2 = bf2f(u.z); v3 = bf2f(u.w);
  }
  float s = v0 + v1 + v2 + v3;
  float sq = v0 * v0 + v1 * v1 + v2 * v2 + v3 * v3;
#pragma unroll
  for (int off = 32; off > 0; off >>= 1) {
    s += __shfl_down(s, off);
    sq += __shfl_down(sq, off);
  }
  __shared__ float ss[4], ssq[4];
  if ((tid & 63) == 0) { ss[tid >> 6] = s; ssq[tid >> 6] = sq; }
  __syncthreads();
  s = ss[0] + ss[1] + ss[2] + ss[3];
  sq = ssq[0] + ssq[1] + ssq[2] + ssq[3];
  const float mean = s * (1.f / 1024.f);
  const float var = (sq - 1024.f * mean * mean) * (1.f / 1023.f);
  const float rs = rsqrtf(var + 1e-5f);
  const int c0 = tid * 4;
  ushort4 o;
  o.x = f2bf(ld_f(gamma, c0 + 0, f) * (v0 - mean) * rs + ld_f(beta, c0 + 0, f));
  o.y = f2bf(ld_f(gamma, c0 + 1, f) * (v1 - mean) * rs + ld_f(beta, c0 + 1, f));
  o.z = f2bf(ld_f(gamma, c0 + 2, f) * (v2 - mean) * rs + ld_f(beta, c0 + 2, f));
  o.w = f2bf(ld_f(gamma, c0 + 3, f) * (v3 - mean) * rs + ld_f(beta, c0 + 3, f));
  *(ushort4*)&out[row * 1024 + tid * 4] = o;
}

extern "C" void kernel_launch(void* const* d_in, const int* in_sizes, int n_in,
                              void* d_out, int out_size, void* d_ws, size_t ws_size,
                              hipStream_t stream) {
  const void* x      = d_in[0];
  const void* Wq     = d_in[1];
  const void* Wk     = d_in[2];
  const void* Wv     = d_in[3];
  const void* W1     = d_in[4];
  const void* b1     = d_in[5];
  const void* W2     = d_in[6];
  const void* b2     = d_in[7];
  const void* gamma1 = d_in[8];
  const void* beta1  = d_in[9];
  const void* gamma2 = d_in[10];
  const void* beta2  = d_in[11];
  u16* ws = (u16*)d_ws;

  const size_t M4 = 4194304;
  u16* h   = ws;
  u16* Qb  = ws + 1 * M4;
  u16* Kb  = ws + 2 * M4;
  u16* Vtb = ws + 3 * M4;   // gemm<0> writes V transposed here directly
  u16* WTq = ws + 4 * M4;
  u16* x2  = ws + 4 * M4;
  u16* h2  = ws + 5 * M4;
  u16* W1T = ws + 6 * M4;
  u16* W2T = ws + 7 * M4;
  u16* ff1 = ws;
  int* flag = (int*)(ws + 8 * M4 + 9216);

  sniff_kernel<<<1, 256, 0, stream>>>((const u16*)x, flag);
  prep_kernel<<<2816, 256, 0, stream>>>(Wq, Wk, Wv, W1, W2, WTq, W1T, W2T, flag);
  ln_kernel<<<4096, 256, 0, stream>>>(x, gamma1, beta1, h, flag, 1);
  gemm_bt<0, 2, 2, false><<<768, 256, 0, stream>>>(h, WTq, 1024, 24, 3072,
                                                   nullptr, nullptr, nullptr,
                                                   Qb, Kb, Vtb, flag);
  attn_mfma<<<1024, 256, 0, stream>>>(Qb, Kb, Vtb, x, flag, x2);
  ln_kernel<<<4096, 256, 0, stream>>>(x2, gamma2, beta2, h2, flag, 0);
  gemm_bt<1, 2, 2, false><<<1024, 256, 0, stream>>>(h2, W1T, 1024, 32, 4096,
                                                    b1, nullptr, ff1,
                                                    nullptr, nullptr, nullptr, flag);
  gemm_bt<2, 2, 1, true><<<512, 128, 0, stream>>>(ff1, W2T, 4096, 32, 1024,
                                                  b2, x2, d_out,
                                                  nullptr, nullptr, nullptr, flag);
}

// Round 13
// 374.908 us; speedup vs baseline: 9.9816x; 1.1156x over previous
//
#include <hip/hip_runtime.h>

typedef unsigned short u16;
typedef __bf16 bf16;
typedef __attribute__((ext_vector_type(8))) __bf16 bf16x8;
typedef __attribute__((ext_vector_type(4))) float f32x4;
typedef __attribute__((ext_vector_type(8))) unsigned short u16x8;
typedef unsigned long long u64;

__device__ __forceinline__ float bf2f(u16 h) {
  return __uint_as_float(((unsigned int)h) << 16);
}
__device__ __forceinline__ u16 f2bf(float f) {
  unsigned int u = __float_as_uint(f);
  return (u16)((u + 0x7fffu + ((u >> 16) & 1u)) >> 16);
}
__device__ __forceinline__ u16 ld_cv(const void* p, size_t i, int f32) {
  return f32 ? f2bf(((const float*)p)[i]) : ((const u16*)p)[i];
}
__device__ __forceinline__ float ld_f(const void* p, size_t i, int f32) {
  return f32 ? ((const float*)p)[i] : bf2f(((const u16*)p)[i]);
}
__device__ __forceinline__ void async16(const u16* g, u16* l) {
  __builtin_amdgcn_global_load_lds(
      (const __attribute__((address_space(1))) unsigned int*)g,
      (__attribute__((address_space(3))) unsigned int*)l, 16, 0, 0);
}
__device__ __forceinline__ unsigned pk_bf16(float hi, float lo) {
  return __builtin_amdgcn_perm(__float_as_uint(hi) + 0x8000u,
                               __float_as_uint(lo) + 0x8000u, 0x07060302u);
}

// ---- dtype sniffer ------------------------------------------------------
__global__ void sniff_kernel(const u16* __restrict__ x, int* __restrict__ flag) {
  const int tid = threadIdx.x;
  int me = 0;
#pragma unroll
  for (int j = 0; j < 4; j++) {
    const u16 v = x[(tid * 4 + j) * 2];
    const int e = (v >> 7) & 0xFF;
    me = me > e ? me : e;
  }
#pragma unroll
  for (int off = 32; off > 0; off >>= 1) {
    const int o = __shfl_down(me, off);
    me = me > o ? me : o;
  }
  __shared__ int sm[4];
  if ((tid & 63) == 0) sm[tid >> 6] = me;
  __syncthreads();
  if (tid == 0) {
    int a = sm[0] > sm[1] ? sm[0] : sm[1];
    int b = sm[2] > sm[3] ? sm[2] : sm[3];
    *flag = ((a > b ? a : b) >= 140) ? 1 : 0;
  }
}

// ---- mega-prep: all three weight transposes in one launch ----------------
__global__ void prep_kernel(const void* __restrict__ Wq, const void* __restrict__ Wk,
                            const void* __restrict__ Wv, const void* __restrict__ W1,
                            const void* __restrict__ W2,
                            u16* __restrict__ WTq, u16* __restrict__ W1T,
                            u16* __restrict__ W2T, const int* __restrict__ flag) {
  __shared__ u16 tile[64][65];
  const int f = *flag;
  const int bid = blockIdx.x;
  const int lx = threadIdx.x & 63, ly = threadIdx.x >> 6;
  if (bid < 768) {
    const int bx = bid & 15, wh = bid >> 4;
    const int w = wh >> 4, hh = wh & 15;
    const int tr = bx * 64;
    const void* W = (w == 0) ? Wq : ((w == 1) ? Wk : Wv);
    const size_t hbase = (size_t)hh * 65536;
#pragma unroll
    for (int i = 0; i < 16; i++)
      tile[ly * 16 + i][lx] = ld_cv(W, hbase + (size_t)(tr + ly * 16 + i) * 64 + lx, f);
    __syncthreads();
#pragma unroll
    for (int i = 0; i < 16; i++)
      WTq[((size_t)(w * 1024 + hh * 64 + ly * 16 + i)) * 1024 + tr + lx] =
          tile[lx][ly * 16 + i];
  } else {
    const void* src;
    u16* dst;
    int R, C, tc, tr;
    if (bid < 1792) {
      const int j = bid - 768;
      src = W1; dst = W1T; R = 1024; C = 4096;
      tc = (j & 63) * 64; tr = (j >> 6) * 64;
    } else {
      const int j = bid - 1792;
      src = W2; dst = W2T; R = 4096; C = 1024;
      tc = (j & 15) * 64; tr = (j >> 4) * 64;
    }
#pragma unroll
    for (int i = 0; i < 16; i++)
      tile[ly * 16 + i][lx] = ld_cv(src, (size_t)(tr + ly * 16 + i) * C + tc + lx, f);
    __syncthreads();
#pragma unroll
    for (int i = 0; i < 16; i++)
      dst[(size_t)(tc + ly * 16 + i) * R + tr + lx] = tile[lx][ly * 16 + i];
  }
}

// ---------------- GEMM: C[m][n] = sum_k A[m][k] * BT[n][k] ----------------
template <int EPI, int WR, int WC, bool MS>
__launch_bounds__(WR * WC * 64)
__global__ void gemm_bt(const u16* __restrict__ A, const u16* __restrict__ B,
                        int K, int NX, int N,
                        const void* __restrict__ bias, const u16* __restrict__ res,
                        void* __restrict__ out,
                        u16* __restrict__ Qo, u16* __restrict__ Ko, u16* __restrict__ Vto,
                        const int* __restrict__ flag) {
  constexpr int BM = WR * 64, BN = WC * 64, T = WR * WC * 64;
  constexpr int RPA = T / 4;
  constexpr int RAH = BM / RPA;
  constexpr int RBH = BN / RPA;
  __shared__ __align__(16) u16 As[BM * 64];
  __shared__ __align__(16) u16 Bs[BN * 64];
  const int tid = threadIdx.x;
  const int bid = blockIdx.x;
  const int sxp = NX >> 3;
  const int xcd = bid & 7, j9 = bid >> 3;
  int m0, n0;
  if (MS) {
    m0 = (xcd * sxp + j9 % sxp) * BM;
    n0 = (j9 / sxp) * BN;
  } else {
    n0 = (xcd * sxp + j9 % sxp) * BN;
    m0 = (j9 / sxp) * BM;
  }
  const int wave = tid >> 6, lane = tid & 63;
  const int wm = (wave / WC) * 64, wn = (wave % WC) * 64;
  const int lm = lane & 15, lq = lane >> 4;
  const int fb = (EPI >= 1) ? *flag : 0;

  const f32x4 zero = {0.f, 0.f, 0.f, 0.f};
  f32x4 acc[4][4];
#pragma unroll
  for (int i = 0; i < 4; i++)
#pragma unroll
    for (int j = 0; j < 4; j++) acc[i][j] = zero;

  const int ar = tid >> 2;
  const int ac = (tid & 3) * 8;
  const u16* Ag = A + (size_t)(m0 + ar) * K + ac;
  const u16* Bg = B + (size_t)(n0 + ar) * K + ac;
  u16* AsP = &As[tid * 8];
  u16* BsP = &Bs[tid * 8];

  for (int k0 = 0; k0 < K; k0 += 64) {
#pragma unroll
    for (int hh = 0; hh < 2; hh++) {
#pragma unroll
      for (int c = 0; c < RAH; c++)
        async16(Ag + k0 + hh * 32 + (size_t)c * RPA * K,
                AsP + hh * BM * 32 + c * RPA * 32);
#pragma unroll
      for (int c = 0; c < RBH; c++)
        async16(Bg + k0 + hh * 32 + (size_t)c * RPA * K,
                BsP + hh * BN * 32 + c * RPA * 32);
    }
    __syncthreads();
    bf16x8 a0[4], a1[4], b0[4], b1[4];
#pragma unroll
    for (int i = 0; i < 4; i++) {
      a0[i] = *(const bf16x8*)&As[(wm + i * 16 + lm) * 32 + lq * 8];
      a1[i] = *(const bf16x8*)&As[BM * 32 + (wm + i * 16 + lm) * 32 + lq * 8];
    }
#pragma unroll
    for (int i = 0; i < 4; i++) {
      b0[i] = *(const bf16x8*)&Bs[(wn + i * 16 + lm) * 32 + lq * 8];
      b1[i] = *(const bf16x8*)&Bs[BN * 32 + (wn + i * 16 + lm) * 32 + lq * 8];
    }
#pragma unroll
    for (int i = 0; i < 4; i++)
#pragma unroll
      for (int j = 0; j < 4; j++) {
        acc[i][j] = __builtin_amdgcn_mfma_f32_16x16x32_bf16(a0[i], b0[j], acc[i][j], 0, 0, 0);
        acc[i][j] = __builtin_amdgcn_mfma_f32_16x16x32_bf16(a1[i], b1[j], acc[i][j], 0, 0, 0);
      }
    __syncthreads();
  }

  if (EPI == 0) {
#pragma unroll
    for (int i = 0; i < 4; i++) {
      const int row0 = m0 + wm + i * 16 + lq * 4;
      const int bb = row0 >> 11, t0 = row0 & 2047;
#pragma unroll
      for (int j = 0; j < 4; j++) {
        const int col = n0 + wn + j * 16 + lm;
        const int w = col >> 10, nn = col & 1023;
        const int hh = nn >> 6, e = nn & 63;
        if (w == 2) {
          ushort4 v4;
          v4.x = f2bf(acc[i][j][0]);
          v4.y = f2bf(acc[i][j][1]);
          v4.z = f2bf(acc[i][j][2]);
          v4.w = f2bf(acc[i][j][3]);
          *(ushort4*)&Vto[(((size_t)(bb * 16 + hh)) * 64 + e) * 2048 + t0] = v4;
        } else {
          u16* dst = (w == 0) ? Qo : Ko;
#pragma unroll
          for (int r = 0; r < 4; r++)
            dst[(((size_t)(bb * 16 + hh)) * 2048 + t0 + r) * 64 + e] =
                f2bf(acc[i][j][r]);
        }
      }
    }
  } else {
#pragma unroll
    for (int i = 0; i < 4; i++) {
#pragma unroll
      for (int r = 0; r < 4; r++) {
        const int row = m0 + wm + i * 16 + lq * 4 + r;
#pragma unroll
        for (int j = 0; j < 4; j++) {
          const int col = n0 + wn + j * 16 + lm;
          const float c = acc[i][j][r];
          if (EPI == 1) {
            const float v = c + ld_f(bias, col, fb);
            ((u16*)out)[(size_t)row * N + col] = f2bf(v > 0.f ? v : 0.f);
          } else {
            const float v = c + ld_f(bias, col, fb) + bf2f(res[(size_t)row * N + col]);
            if (fb)
              ((float*)out)[(size_t)row * N + col] = v;
            else
              ((u16*)out)[(size_t)row * N + col] = f2bf(v);
          }
        }
      }
    }
  }
}

// ---------------- MFMA flash attention v8b: phases + LDS-staged K/V --------
// Same as v8 but with a __syncthreads BEFORE the merge writes: Olds aliases
// the per-wave staging LDS (Olds[w] spans 8704B vs 8KB staging regions, so
// Olds[w] bleeds into wave w+1's staging). v8 wrote partials while other
// waves were still staging -> corrupted K fragments -> exp(huge) -> NaN.
// The pre-merge barrier makes the aliased region dead before any write
// (every wave has drained vmcnt(0) after its last staging batch).
__launch_bounds__(256)
__global__ void attn_mfma(const u16* __restrict__ Q, const u16* __restrict__ K,
                          const u16* __restrict__ Vt, const void* __restrict__ xres,
                          const int* __restrict__ flag, u16* __restrict__ x2) {
  __shared__ __align__(16) unsigned char smem[35328];
  const int tid = threadIdx.x;
  const int wave = tid >> 6, lane = tid & 63;
  const int lm = lane & 15, quad = lane >> 4;
  const int bid = blockIdx.x;
  const int xcd = bid & 7, jj = bid >> 3;
  const int bh = xcd + 8 * (jj & 3);
  const int pair = jj >> 2;  // 0..31
  const int b = bh >> 4, h = bh & 15;
  const int f32in = *flag;

  u16* stw = (u16*)smem + wave * 4096;  // 8KB per wave
  u16* Ksw = stw;                        // [half][32][32]
  u16* Vsw = stw + 2048;                 // [64][32]
  float (*Olds)[32][68] = (float(*)[32][68])smem;          // 34816 B
  float (*Llds)[2][16] = (float(*)[2][16])(smem + 34816);  // 512 B

  const u16* Kbh = K + (size_t)bh * 131072;
  const u16* Vbh = Vt + (size_t)bh * 131072;
  const f32x4 zero = {0.f, 0.f, 0.f, 0.f};
  const int srow = lane >> 2;        // staging row 0..15
  const int schk = (lane & 3) * 8;   // staging col chunk

  union V8 { bf16x8 v; struct { u64 lo, hi; } q; };

#pragma unroll 1
  for (int phase = 0; phase < 2; phase++) {
    const int qb = phase ? (63 - pair) : pair;
    const int qw0 = qb * 32;

    bf16x8 qf[2][2];
#pragma unroll
    for (int s = 0; s < 2; s++) {
      const u16* Qp = Q + ((size_t)bh * 2048 + qw0 + s * 16 + lm) * 64 + quad * 8;
      qf[s][0] = *(const bf16x8*)Qp;
      qf[s][1] = *(const bf16x8*)(Qp + 32);
    }
    f32x4 ot[2][4];
#pragma unroll
    for (int s = 0; s < 2; s++)
#pragma unroll
      for (int j = 0; j < 4; j++) ot[s][j] = zero;
    float l[2] = {0.f, 0.f};

    const int nt = qb + 1;
    const int si = (nt * wave) >> 2;
    const int ei = (nt * (wave + 1)) >> 2;

    for (int t = si; t < ei; t++) {
      const int ks = t * 32;
#pragma unroll
      for (int hh2 = 0; hh2 < 2; hh2++)
#pragma unroll
        for (int c = 0; c < 2; c++)
          async16(Kbh + (size_t)(ks + c * 16 + srow) * 64 + hh2 * 32 + schk,
                  Ksw + hh2 * 1024 + c * 512 + lane * 8);
#pragma unroll
      for (int c = 0; c < 4; c++)
        async16(Vbh + (size_t)(c * 16 + srow) * 2048 + ks + schk,
                Vsw + c * 512 + lane * 8);
      __builtin_amdgcn_s_waitcnt(0x0F70);  // vmcnt(0): staging landed

      // S^T = K x Q^T
      f32x4 S[2][2];
#pragma unroll
      for (int s = 0; s < 2; s++)
#pragma unroll
        for (int hh = 0; hh < 2; hh++) {
          const bf16x8 k0 = *(const bf16x8*)&Ksw[(hh * 16 + lm) * 32 + quad * 8];
          const bf16x8 k1 = *(const bf16x8*)&Ksw[1024 + (hh * 16 + lm) * 32 + quad * 8];
          f32x4 a = zero;
          a = __builtin_amdgcn_mfma_f32_16x16x32_bf16(k0, qf[s][0], a, 0, 0, 0);
          a = __builtin_amdgcn_mfma_f32_16x16x32_bf16(k1, qf[s][1], a, 0, 0, 0);
          S[s][hh] = a;
        }
      const bool maskT = (t == qb);
#pragma unroll
      for (int s = 0; s < 2; s++) {
        float p[2][4];
#pragma unroll
        for (int hh = 0; hh < 2; hh++)
#pragma unroll
          for (int r = 0; r < 4; r++) {
            float v = __expf(S[s][hh][r] * 0.03125f);
            if (maskT && (hh * 16 + quad * 4 + r > s * 16 + lm)) v = 0.f;
            l[s] += v;
            p[hh][r] = v;
          }
        unsigned pk[4];
        pk[0] = pk_bf16(p[0][1], p[0][0]);
        pk[1] = pk_bf16(p[0][3], p[0][2]);
        pk[2] = pk_bf16(p[1][1], p[1][0]);
        pk[3] = pk_bf16(p[1][3], p[1][2]);
        const bf16x8 pf = *(const bf16x8*)pk;
#pragma unroll
        for (int j = 0; j < 4; j++) {
          V8 vf;
          vf.q.lo = *(const u64*)&Vsw[(j * 16 + lm) * 32 + quad * 4];
          vf.q.hi = *(const u64*)&Vsw[(j * 16 + lm) * 32 + 16 + quad * 4];
          ot[s][j] = __builtin_amdgcn_mfma_f32_16x16x32_bf16(vf.v, pf, ot[s][j], 0, 0, 0);
        }
      }
    }

#pragma unroll
    for (int s = 0; s < 2; s++) {
      l[s] += __shfl_xor(l[s], 16);
      l[s] += __shfl_xor(l[s], 32);
    }

    __syncthreads();  // ALL waves done staging/reading before Olds overwrite

#pragma unroll
    for (int s = 0; s < 2; s++)
#pragma unroll
      for (int j = 0; j < 4; j++)
        *(f32x4*)&Olds[wave][s * 16 + lm][j * 16 + quad * 4] = ot[s][j];
    if (quad == 0) {
      Llds[wave][0][lm] = l[0];
      Llds[wave][1][lm] = l[1];
    }
    __syncthreads();
    const int q = tid >> 3;
    const int e0 = (tid & 7) * 8;
    f32x4 oa = zero, ob = zero;
#pragma unroll
    for (int w = 0; w < 4; w++) {
      oa += *(const f32x4*)&Olds[w][q][e0];
      ob += *(const f32x4*)&Olds[w][q][e0 + 4];
    }
    const float lt = Llds[0][q >> 4][q & 15] + Llds[1][q >> 4][q & 15] +
                     Llds[2][q >> 4][q & 15] + Llds[3][q >> 4][q & 15];
    const float linv = 1.f / lt;
    const size_t rowbase = ((size_t)(b * 2048 + qw0 + q)) * 1024 + h * 64 + e0;
    float xv[8];
    if (f32in) {
      const float* xf = (const float*)xres + rowbase;
      const float4 u0 = *(const float4*)xf;
      const float4 u1 = *(const float4*)(xf + 4);
      xv[0] = u0.x; xv[1] = u0.y; xv[2] = u0.z; xv[3] = u0.w;
      xv[4] = u1.x; xv[5] = u1.y; xv[6] = u1.z; xv[7] = u1.w;
    } else {
      const u16x8 u = *(const u16x8*)((const u16*)xres + rowbase);
#pragma unroll
      for (int k = 0; k < 8; k++) xv[k] = bf2f(u[k]);
    }
    u16x8 o8;
#pragma unroll
    for (int k = 0; k < 4; k++) o8[k] = f2bf(xv[k] + oa[k] * linv);
#pragma unroll
    for (int k = 0; k < 4; k++) o8[4 + k] = f2bf(xv[4 + k] + ob[k] * linv);
    *(u16x8*)&x2[rowbase] = o8;
    __syncthreads();  // all merge reads done before next phase's staging
  }
}

// ---------------- LayerNorm (ddof=1, eps=1e-5), raw dual-dtype inputs ------
__launch_bounds__(256)
__global__ void ln_kernel(const void* __restrict__ x, const void* __restrict__ gamma,
                          const void* __restrict__ beta, u16* __restrict__ out,
                          const int* __restrict__ flag, int xraw) {
  const size_t row = blockIdx.x;
  const int tid = threadIdx.x;
  const int f = *flag;
  const int fx = xraw ? f : 0;
  float v0, v1, v2, v3;
  if (fx) {
    const float4 v = *((const float4*)x + row * 256 + tid);
    v0 = v.x; v1 = v.y; v2 = v.z; v3 = v.w;
  } else {
    const ushort4 u = *((const ushort4*)x + row * 256 + tid);
    v0 = bf2f(u.x); v1 = bf2f(u.y); v2 = bf2f(u.z); v3 = bf2f(u.w);
  }
  float s = v0 + v1 + v2 + v3;
  float sq = v0 * v0 + v1 * v1 + v2 * v2 + v3 * v3;
#pragma unroll
  for (int off = 32; off > 0; off >>= 1) {
    s += __shfl_down(s, off);
    sq += __shfl_down(sq, off);
  }
  __shared__ float ss[4], ssq[4];
  if ((tid & 63) == 0) { ss[tid >> 6] = s; ssq[tid >> 6] = sq; }
  __syncthreads();
  s = ss[0] + ss[1] + ss[2] + ss[3];
  sq = ssq[0] + ssq[1] + ssq[2] + ssq[3];
  const float mean = s * (1.f / 1024.f);
  const float var = (sq - 1024.f * mean * mean) * (1.f / 1023.f);
  const float rs = rsqrtf(var + 1e-5f);
  const int c0 = tid * 4;
  ushort4 o;
  o.x = f2bf(ld_f(gamma, c0 + 0, f) * (v0 - mean) * rs + ld_f(beta, c0 + 0, f));
  o.y = f2bf(ld_f(gamma, c0 + 1, f) * (v1 - mean) * rs + ld_f(beta, c0 + 1, f));
  o.z = f2bf(ld_f(gamma, c0 + 2, f) * (v2 - mean) * rs + ld_f(beta, c0 + 2, f));
  o.w = f2bf(ld_f(gamma, c0 + 3, f) * (v3 - mean) * rs + ld_f(beta, c0 + 3, f));
  *(ushort4*)&out[row * 1024 + tid * 4] = o;
}

extern "C" void kernel_launch(void* const* d_in, const int* in_sizes, int n_in,
                              void* d_out, int out_size, void* d_ws, size_t ws_size,
                              hipStream_t stream) {
  const void* x      = d_in[0];
  const void* Wq     = d_in[1];
  const void* Wk     = d_in[2];
  const void* Wv     = d_in[3];
  const void* W1     = d_in[4];
  const void* b1     = d_in[5];
  const void* W2     = d_in[6];
  const void* b2     = d_in[7];
  const void* gamma1 = d_in[8];
  const void* beta1  = d_in[9];
  const void* gamma2 = d_in[10];
  const void* beta2  = d_in[11];
  u16* ws = (u16*)d_ws;

  const size_t M4 = 4194304;
  u16* h   = ws;
  u16* Qb  = ws + 1 * M4;
  u16* Kb  = ws + 2 * M4;
  u16* Vtb = ws + 3 * M4;
  u16* WTq = ws + 4 * M4;
  u16* x2  = ws + 4 * M4;
  u16* h2  = ws + 5 * M4;
  u16* W1T = ws + 6 * M4;
  u16* W2T = ws + 7 * M4;
  u16* ff1 = ws;
  int* flag = (int*)(ws + 8 * M4 + 9216);

  sniff_kernel<<<1, 256, 0, stream>>>((const u16*)x, flag);
  prep_kernel<<<2816, 256, 0, stream>>>(Wq, Wk, Wv, W1, W2, WTq, W1T, W2T, flag);
  ln_kernel<<<4096, 256, 0, stream>>>(x, gamma1, beta1, h, flag, 1);
  gemm_bt<0, 2, 2, false><<<768, 256, 0, stream>>>(h, WTq, 1024, 24, 3072,
                                                   nullptr, nullptr, nullptr,
                                                   Qb, Kb, Vtb, flag);
  attn_mfma<<<1024, 256, 0, stream>>>(Qb, Kb, Vtb, x, flag, x2);
  ln_kernel<<<4096, 256, 0, stream>>>(x2, gamma2, beta2, h2, flag, 0);
  gemm_bt<1, 2, 2, false><<<1024, 256, 0, stream>>>(h2, W1T, 1024, 32, 4096,
                                                    b1, nullptr, ff1,
                                                    nullptr, nullptr, nullptr, flag);
  gemm_bt<2, 2, 1, true><<<512, 128, 0, stream>>>(ff1, W2T, 4096, 32, 1024,
                                                  b2, x2, d_out,
                                                  nullptr, nullptr, nullptr, flag);
}

// Round 14
// 350.829 us; speedup vs baseline: 10.6666x; 1.0686x over previous
//
#include <hip/hip_runtime.h>

typedef unsigned short u16;
typedef __bf16 bf16;
typedef __attribute__((ext_vector_type(8))) __bf16 bf16x8;
typedef __attribute__((ext_vector_type(4))) float f32x4;
typedef __attribute__((ext_vector_type(8))) unsigned short u16x8;
typedef unsigned long long u64;

__device__ __forceinline__ float bf2f(u16 h) {
  return __uint_as_float(((unsigned int)h) << 16);
}
__device__ __forceinline__ u16 f2bf(float f) {
  unsigned int u = __float_as_uint(f);
  return (u16)((u + 0x7fffu + ((u >> 16) & 1u)) >> 16);
}
__device__ __forceinline__ u16 ld_cv(const void* p, size_t i, int f32) {
  return f32 ? f2bf(((const float*)p)[i]) : ((const u16*)p)[i];
}
__device__ __forceinline__ float ld_f(const void* p, size_t i, int f32) {
  return f32 ? ((const float*)p)[i] : bf2f(((const u16*)p)[i]);
}
__device__ __forceinline__ void async16(const u16* g, u16* l) {
  __builtin_amdgcn_global_load_lds(
      (const __attribute__((address_space(1))) unsigned int*)g,
      (__attribute__((address_space(3))) unsigned int*)l, 16, 0, 0);
}
__device__ __forceinline__ unsigned pk_bf16(float hi, float lo) {
  return __builtin_amdgcn_perm(__float_as_uint(hi) + 0x8000u,
                               __float_as_uint(lo) + 0x8000u, 0x07060302u);
}

// ---- dtype sniffer ------------------------------------------------------
__global__ void sniff_kernel(const u16* __restrict__ x, int* __restrict__ flag) {
  const int tid = threadIdx.x;
  int me = 0;
#pragma unroll
  for (int j = 0; j < 4; j++) {
    const u16 v = x[(tid * 4 + j) * 2];
    const int e = (v >> 7) & 0xFF;
    me = me > e ? me : e;
  }
#pragma unroll
  for (int off = 32; off > 0; off >>= 1) {
    const int o = __shfl_down(me, off);
    me = me > o ? me : o;
  }
  __shared__ int sm[4];
  if ((tid & 63) == 0) sm[tid >> 6] = me;
  __syncthreads();
  if (tid == 0) {
    int a = sm[0] > sm[1] ? sm[0] : sm[1];
    int b = sm[2] > sm[3] ? sm[2] : sm[3];
    *flag = ((a > b ? a : b) >= 140) ? 1 : 0;
  }
}

// ---- mega-prep: all three weight transposes in one launch ----------------
__global__ void prep_kernel(const void* __restrict__ Wq, const void* __restrict__ Wk,
                            const void* __restrict__ Wv, const void* __restrict__ W1,
                            const void* __restrict__ W2,
                            u16* __restrict__ WTq, u16* __restrict__ W1T,
                            u16* __restrict__ W2T, const int* __restrict__ flag) {
  __shared__ u16 tile[64][65];
  const int f = *flag;
  const int bid = blockIdx.x;
  const int lx = threadIdx.x & 63, ly = threadIdx.x >> 6;
  if (bid < 768) {
    const int bx = bid & 15, wh = bid >> 4;
    const int w = wh >> 4, hh = wh & 15;
    const int tr = bx * 64;
    const void* W = (w == 0) ? Wq : ((w == 1) ? Wk : Wv);
    const size_t hbase = (size_t)hh * 65536;
#pragma unroll
    for (int i = 0; i < 16; i++)
      tile[ly * 16 + i][lx] = ld_cv(W, hbase + (size_t)(tr + ly * 16 + i) * 64 + lx, f);
    __syncthreads();
#pragma unroll
    for (int i = 0; i < 16; i++)
      WTq[((size_t)(w * 1024 + hh * 64 + ly * 16 + i)) * 1024 + tr + lx] =
          tile[lx][ly * 16 + i];
  } else {
    const void* src;
    u16* dst;
    int R, C, tc, tr;
    if (bid < 1792) {
      const int j = bid - 768;
      src = W1; dst = W1T; R = 1024; C = 4096;
      tc = (j & 63) * 64; tr = (j >> 6) * 64;
    } else {
      const int j = bid - 1792;
      src = W2; dst = W2T; R = 4096; C = 1024;
      tc = (j & 15) * 64; tr = (j >> 4) * 64;
    }
#pragma unroll
    for (int i = 0; i < 16; i++)
      tile[ly * 16 + i][lx] = ld_cv(src, (size_t)(tr + ly * 16 + i) * C + tc + lx, f);
    __syncthreads();
#pragma unroll
    for (int i = 0; i < 16; i++)
      dst[(size_t)(tc + ly * 16 + i) * R + tr + lx] = tile[lx][ly * 16 + i];
  }
}

// ---------------- GEMM: C[m][n] = sum_k A[m][k] * BT[n][k] ----------------
// Tile BM(=WR*64) x BN(=WC*64); BK=64 as two BK=32 halves, one barrier pair.
template <int EPI, int WR, int WC, bool MS>
__launch_bounds__(WR * WC * 64)
__global__ void gemm_bt(const u16* __restrict__ A, const u16* __restrict__ B,
                        int K, int NX, int N,
                        const void* __restrict__ bias, const u16* __restrict__ res,
                        void* __restrict__ out,
                        u16* __restrict__ Qo, u16* __restrict__ Ko, u16* __restrict__ Vto,
                        const int* __restrict__ flag) {
  constexpr int BM = WR * 64, BN = WC * 64, T = WR * WC * 64;
  constexpr int RPA = T / 4;
  constexpr int RAH = BM / RPA;
  constexpr int RBH = BN / RPA;
  __shared__ __align__(16) u16 As[BM * 64];
  __shared__ __align__(16) u16 Bs[BN * 64];
  const int tid = threadIdx.x;
  const int bid = blockIdx.x;
  const int sxp = NX >> 3;
  const int xcd = bid & 7, j9 = bid >> 3;
  int m0, n0;
  if (MS) {
    m0 = (xcd * sxp + j9 % sxp) * BM;
    n0 = (j9 / sxp) * BN;
  } else {
    n0 = (xcd * sxp + j9 % sxp) * BN;
    m0 = (j9 / sxp) * BM;
  }
  const int wave = tid >> 6, lane = tid & 63;
  const int wm = (wave / WC) * 64, wn = (wave % WC) * 64;
  const int lm = lane & 15, lq = lane >> 4;
  const int fb = (EPI >= 1) ? *flag : 0;

  const f32x4 zero = {0.f, 0.f, 0.f, 0.f};
  f32x4 acc[4][4];
#pragma unroll
  for (int i = 0; i < 4; i++)
#pragma unroll
    for (int j = 0; j < 4; j++) acc[i][j] = zero;

  const int ar = tid >> 2;
  const int ac = (tid & 3) * 8;
  const u16* Ag = A + (size_t)(m0 + ar) * K + ac;
  const u16* Bg = B + (size_t)(n0 + ar) * K + ac;
  u16* AsP = &As[tid * 8];
  u16* BsP = &Bs[tid * 8];

  for (int k0 = 0; k0 < K; k0 += 64) {
#pragma unroll
    for (int hh = 0; hh < 2; hh++) {
#pragma unroll
      for (int c = 0; c < RAH; c++)
        async16(Ag + k0 + hh * 32 + (size_t)c * RPA * K,
                AsP + hh * BM * 32 + c * RPA * 32);
#pragma unroll
      for (int c = 0; c < RBH; c++)
        async16(Bg + k0 + hh * 32 + (size_t)c * RPA * K,
                BsP + hh * BN * 32 + c * RPA * 32);
    }
    __syncthreads();
    bf16x8 a0[4], a1[4], b0[4], b1[4];
#pragma unroll
    for (int i = 0; i < 4; i++) {
      a0[i] = *(const bf16x8*)&As[(wm + i * 16 + lm) * 32 + lq * 8];
      a1[i] = *(const bf16x8*)&As[BM * 32 + (wm + i * 16 + lm) * 32 + lq * 8];
    }
#pragma unroll
    for (int i = 0; i < 4; i++) {
      b0[i] = *(const bf16x8*)&Bs[(wn + i * 16 + lm) * 32 + lq * 8];
      b1[i] = *(const bf16x8*)&Bs[BN * 32 + (wn + i * 16 + lm) * 32 + lq * 8];
    }
#pragma unroll
    for (int i = 0; i < 4; i++)
#pragma unroll
      for (int j = 0; j < 4; j++) {
        acc[i][j] = __builtin_amdgcn_mfma_f32_16x16x32_bf16(a0[i], b0[j], acc[i][j], 0, 0, 0);
        acc[i][j] = __builtin_amdgcn_mfma_f32_16x16x32_bf16(a1[i], b1[j], acc[i][j], 0, 0, 0);
      }
    __syncthreads();
  }

  if (EPI == 0) {
#pragma unroll
    for (int i = 0; i < 4; i++) {
      const int row0 = m0 + wm + i * 16 + lq * 4;
      const int bb = row0 >> 11, t0 = row0 & 2047;
#pragma unroll
      for (int j = 0; j < 4; j++) {
        const int col = n0 + wn + j * 16 + lm;
        const int w = col >> 10, nn = col & 1023;
        const int hh = nn >> 6, e = nn & 63;
        if (w == 2) {
          ushort4 v4;
          v4.x = f2bf(acc[i][j][0]);
          v4.y = f2bf(acc[i][j][1]);
          v4.z = f2bf(acc[i][j][2]);
          v4.w = f2bf(acc[i][j][3]);
          *(ushort4*)&Vto[(((size_t)(bb * 16 + hh)) * 64 + e) * 2048 + t0] = v4;
        } else {
          u16* dst = (w == 0) ? Qo : Ko;
#pragma unroll
          for (int r = 0; r < 4; r++)
            dst[(((size_t)(bb * 16 + hh)) * 2048 + t0 + r) * 64 + e] =
                f2bf(acc[i][j][r]);
        }
      }
    }
  } else {
#pragma unroll
    for (int i = 0; i < 4; i++) {
#pragma unroll
      for (int r = 0; r < 4; r++) {
        const int row = m0 + wm + i * 16 + lq * 4 + r;
#pragma unroll
        for (int j = 0; j < 4; j++) {
          const int col = n0 + wn + j * 16 + lm;
          const float c = acc[i][j][r];
          if (EPI == 1) {
            const float v = c + ld_f(bias, col, fb);
            ((u16*)out)[(size_t)row * N + col] = f2bf(v > 0.f ? v : 0.f);
          } else {
            const float v = c + ld_f(bias, col, fb) + bf2f(res[(size_t)row * N + col]);
            if (fb)
              ((float*)out)[(size_t)row * N + col] = v;
            else
              ((u16*)out)[(size_t)row * N + col] = f2bf(v);
          }
        }
      }
    }
  }
}

// ---------------- gemm_sk: FFN2 with in-block split-K ----------------------
// C[4096][1024] = ff1[4096][4096] x W2T^T + b2 + res. Tile 128x64, 4 waves:
// wave w: m-half (w&1), k-half (w>>1) of K=4096. Same staged bytes/MFMA as
// the 2-wave version but 2x resident waves. kh=1 partials merged via LDS
// (aliased with staging; barrier before merge writes).
__launch_bounds__(256)
__global__ void gemm_sk(const u16* __restrict__ A, const u16* __restrict__ B,
                        const void* __restrict__ bias, const u16* __restrict__ res,
                        void* __restrict__ out, const int* __restrict__ flag) {
  __shared__ __align__(16) unsigned char smem[33536];
  u16* As = (u16*)smem;            // [kh][128][32] = 8192 u16
  u16* Bs = (u16*)smem + 8192;     // [kh][64][32]  = 4096 u16
  float* Ml = (float*)smem;        // [2][64][65] merge (aliased)
  const int tid = threadIdx.x;
  const int bid = blockIdx.x;
  const int xcd = bid & 7, j9 = bid >> 3;
  const int m0 = (xcd * 4 + j9 % 4) * 128;  // m-strip per XCD (A stays hot)
  const int n0 = (j9 / 4) * 64;
  const int wave = tid >> 6, lane = tid & 63;
  const int wm = (wave & 1) * 64, kh = wave >> 1;
  const int lm = lane & 15, lq = lane >> 4;
  const int fb = *flag;

  const f32x4 zero = {0.f, 0.f, 0.f, 0.f};
  f32x4 acc[4][4];
#pragma unroll
  for (int i = 0; i < 4; i++)
#pragma unroll
    for (int j = 0; j < 4; j++) acc[i][j] = zero;

  const int ar = tid >> 2;        // 0..63
  const int ac = (tid & 3) * 8;
  const u16* Ag = A + (size_t)(m0 + ar) * 4096 + ac;
  const u16* Bg = B + (size_t)(n0 + ar) * 4096 + ac;
  const int khash = kh * 4096;    // u16 offset of this wave's As k-half
  const int khbs = kh * 2048;

  for (int k0 = 0; k0 < 2048; k0 += 32) {
#pragma unroll
    for (int khh = 0; khh < 2; khh++) {
#pragma unroll
      for (int c = 0; c < 2; c++)
        async16(Ag + khh * 2048 + k0 + (size_t)c * 64 * 4096,
                As + khh * 4096 + c * 2048 + tid * 8);
      async16(Bg + khh * 2048 + k0, Bs + khh * 2048 + tid * 8);
    }
    __syncthreads();
    bf16x8 a[4], b[4];
#pragma unroll
    for (int i = 0; i < 4; i++)
      a[i] = *(const bf16x8*)&As[khash + (wm + i * 16 + lm) * 32 + lq * 8];
#pragma unroll
    for (int j = 0; j < 4; j++)
      b[j] = *(const bf16x8*)&Bs[khbs + (j * 16 + lm) * 32 + lq * 8];
#pragma unroll
    for (int i = 0; i < 4; i++)
#pragma unroll
      for (int j = 0; j < 4; j++)
        acc[i][j] = __builtin_amdgcn_mfma_f32_16x16x32_bf16(a[i], b[j], acc[i][j], 0, 0, 0);
    __syncthreads();
  }

  // merge k-halves: kh=1 writes partials, kh=0 adds + epilogue
  __syncthreads();  // redundant-safe: all staging/reads drained
  if (kh == 1) {
    const int mh = wave & 1;
#pragma unroll
    for (int i = 0; i < 4; i++)
#pragma unroll
      for (int j = 0; j < 4; j++)
#pragma unroll
        for (int r = 0; r < 4; r++)
          Ml[mh * 4160 + (i * 16 + lq * 4 + r) * 65 + j * 16 + lm] = acc[i][j][r];
  }
  __syncthreads();
  if (kh == 0) {
    const int mh = wave & 1;
#pragma unroll
    for (int i = 0; i < 4; i++) {
#pragma unroll
      for (int r = 0; r < 4; r++) {
        const int row = m0 + wm + i * 16 + lq * 4 + r;
#pragma unroll
        for (int j = 0; j < 4; j++) {
          const int col = n0 + j * 16 + lm;
          const float c = acc[i][j][r] +
                          Ml[mh * 4160 + (i * 16 + lq * 4 + r) * 65 + j * 16 + lm];
          const float v = c + ld_f(bias, col, fb) + bf2f(res[(size_t)row * 1024 + col]);
          if (fb)
            ((float*)out)[(size_t)row * 1024 + col] = v;
          else
            ((u16*)out)[(size_t)row * 1024 + col] = f2bf(v);
        }
      }
    }
  }
}

// ---------------- MFMA flash attention v8b: phases + LDS-staged K/V --------
__launch_bounds__(256)
__global__ void attn_mfma(const u16* __restrict__ Q, const u16* __restrict__ K,
                          const u16* __restrict__ Vt, const void* __restrict__ xres,
                          const int* __restrict__ flag, u16* __restrict__ x2) {
  __shared__ __align__(16) unsigned char smem[35328];
  const int tid = threadIdx.x;
  const int wave = tid >> 6, lane = tid & 63;
  const int lm = lane & 15, quad = lane >> 4;
  const int bid = blockIdx.x;
  const int xcd = bid & 7, jj = bid >> 3;
  const int bh = xcd + 8 * (jj & 3);
  const int pair = jj >> 2;  // 0..31
  const int b = bh >> 4, h = bh & 15;
  const int f32in = *flag;

  u16* stw = (u16*)smem + wave * 4096;  // 8KB per wave
  u16* Ksw = stw;                        // [half][32][32]
  u16* Vsw = stw + 2048;                 // [64][32]
  float (*Olds)[32][68] = (float(*)[32][68])smem;          // 34816 B
  float (*Llds)[2][16] = (float(*)[2][16])(smem + 34816);  // 512 B

  const u16* Kbh = K + (size_t)bh * 131072;
  const u16* Vbh = Vt + (size_t)bh * 131072;
  const f32x4 zero = {0.f, 0.f, 0.f, 0.f};
  const int srow = lane >> 2;
  const int schk = (lane & 3) * 8;

  union V8 { bf16x8 v; struct { u64 lo, hi; } q; };

#pragma unroll 1
  for (int phase = 0; phase < 2; phase++) {
    const int qb = phase ? (63 - pair) : pair;
    const int qw0 = qb * 32;

    bf16x8 qf[2][2];
#pragma unroll
    for (int s = 0; s < 2; s++) {
      const u16* Qp = Q + ((size_t)bh * 2048 + qw0 + s * 16 + lm) * 64 + quad * 8;
      qf[s][0] = *(const bf16x8*)Qp;
      qf[s][1] = *(const bf16x8*)(Qp + 32);
    }
    f32x4 ot[2][4];
#pragma unroll
    for (int s = 0; s < 2; s++)
#pragma unroll
      for (int j = 0; j < 4; j++) ot[s][j] = zero;
    float l[2] = {0.f, 0.f};

    const int nt = qb + 1;
    const int si = (nt * wave) >> 2;
    const int ei = (nt * (wave + 1)) >> 2;

    for (int t = si; t < ei; t++) {
      const int ks = t * 32;
#pragma unroll
      for (int hh2 = 0; hh2 < 2; hh2++)
#pragma unroll
        for (int c = 0; c < 2; c++)
          async16(Kbh + (size_t)(ks + c * 16 + srow) * 64 + hh2 * 32 + schk,
                  Ksw + hh2 * 1024 + c * 512 + lane * 8);
#pragma unroll
      for (int c = 0; c < 4; c++)
        async16(Vbh + (size_t)(c * 16 + srow) * 2048 + ks + schk,
                Vsw + c * 512 + lane * 8);
      __builtin_amdgcn_s_waitcnt(0x0F70);  // vmcnt(0)

      f32x4 S[2][2];
#pragma unroll
      for (int s = 0; s < 2; s++)
#pragma unroll
        for (int hh = 0; hh < 2; hh++) {
          const bf16x8 k0 = *(const bf16x8*)&Ksw[(hh * 16 + lm) * 32 + quad * 8];
          const bf16x8 k1 = *(const bf16x8*)&Ksw[1024 + (hh * 16 + lm) * 32 + quad * 8];
          f32x4 a = zero;
          a = __builtin_amdgcn_mfma_f32_16x16x32_bf16(k0, qf[s][0], a, 0, 0, 0);
          a = __builtin_amdgcn_mfma_f32_16x16x32_bf16(k1, qf[s][1], a, 0, 0, 0);
          S[s][hh] = a;
        }
      const bool maskT = (t == qb);
#pragma unroll
      for (int s = 0; s < 2; s++) {
        float p[2][4];
#pragma unroll
        for (int hh = 0; hh < 2; hh++)
#pragma unroll
          for (int r = 0; r < 4; r++) {
            float v = __expf(S[s][hh][r] * 0.03125f);
            if (maskT && (hh * 16 + quad * 4 + r > s * 16 + lm)) v = 0.f;
            l[s] += v;
            p[hh][r] = v;
          }
        unsigned pk[4];
        pk[0] = pk_bf16(p[0][1], p[0][0]);
        pk[1] = pk_bf16(p[0][3], p[0][2]);
        pk[2] = pk_bf16(p[1][1], p[1][0]);
        pk[3] = pk_bf16(p[1][3], p[1][2]);
        const bf16x8 pf = *(const bf16x8*)pk;
#pragma unroll
        for (int j = 0; j < 4; j++) {
          V8 vf;
          vf.q.lo = *(const u64*)&Vsw[(j * 16 + lm) * 32 + quad * 4];
          vf.q.hi = *(const u64*)&Vsw[(j * 16 + lm) * 32 + 16 + quad * 4];
          ot[s][j] = __builtin_amdgcn_mfma_f32_16x16x32_bf16(vf.v, pf, ot[s][j], 0, 0, 0);
        }
      }
    }

#pragma unroll
    for (int s = 0; s < 2; s++) {
      l[s] += __shfl_xor(l[s], 16);
      l[s] += __shfl_xor(l[s], 32);
    }

    __syncthreads();  // ALL waves done staging/reading before Olds overwrite

#pragma unroll
    for (int s = 0; s < 2; s++)
#pragma unroll
      for (int j = 0; j < 4; j++)
        *(f32x4*)&Olds[wave][s * 16 + lm][j * 16 + quad * 4] = ot[s][j];
    if (quad == 0) {
      Llds[wave][0][lm] = l[0];
      Llds[wave][1][lm] = l[1];
    }
    __syncthreads();
    const int q = tid >> 3;
    const int e0 = (tid & 7) * 8;
    f32x4 oa = zero, ob = zero;
#pragma unroll
    for (int w = 0; w < 4; w++) {
      oa += *(const f32x4*)&Olds[w][q][e0];
      ob += *(const f32x4*)&Olds[w][q][e0 + 4];
    }
    const float lt = Llds[0][q >> 4][q & 15] + Llds[1][q >> 4][q & 15] +
                     Llds[2][q >> 4][q & 15] + Llds[3][q >> 4][q & 15];
    const float linv = 1.f / lt;
    const size_t rowbase = ((size_t)(b * 2048 + qw0 + q)) * 1024 + h * 64 + e0;
    float xv[8];
    if (f32in) {
      const float* xf = (const float*)xres + rowbase;
      const float4 u0 = *(const float4*)xf;
      const float4 u1 = *(const float4*)(xf + 4);
      xv[0] = u0.x; xv[1] = u0.y; xv[2] = u0.z; xv[3] = u0.w;
      xv[4] = u1.x; xv[5] = u1.y; xv[6] = u1.z; xv[7] = u1.w;
    } else {
      const u16x8 u = *(const u16x8*)((const u16*)xres + rowbase);
#pragma unroll
      for (int k = 0; k < 8; k++) xv[k] = bf2f(u[k]);
    }
    u16x8 o8;
#pragma unroll
    for (int k = 0; k < 4; k++) o8[k] = f2bf(xv[k] + oa[k] * linv);
#pragma unroll
    for (int k = 0; k < 4; k++) o8[4 + k] = f2bf(xv[4 + k] + ob[k] * linv);
    *(u16x8*)&x2[rowbase] = o8;
    __syncthreads();
  }
}

// ---------------- LayerNorm (ddof=1, eps=1e-5), raw dual-dtype inputs ------
__launch_bounds__(256)
__global__ void ln_kernel(const void* __restrict__ x, const void* __restrict__ gamma,
                          const void* __restrict__ beta, u16* __restrict__ out,
                          const int* __restrict__ flag, int xraw) {
  const size_t row = blockIdx.x;
  const int tid = threadIdx.x;
  const int f = *flag;
  const int fx = xraw ? f : 0;
  float v0, v1, v2, v3;
  if (fx) {
    const float4 v = *((const float4*)x + row * 256 + tid);
    v0 = v.x; v1 = v.y; v2 = v.z; v3 = v.w;
  } else {
    const ushort4 u = *((const ushort4*)x + row * 256 + tid);
    v0 = bf2f(u.x); v1 = bf2f(u.y); v2 = bf2f(u.z); v3 = bf2f(u.w);
  }
  float s = v0 + v1 + v2 + v3;
  float sq = v0 * v0 + v1 * v1 + v2 * v2 + v3 * v3;
#pragma unroll
  for (int off = 32; off > 0; off >>= 1) {
    s += __shfl_down(s, off);
    sq += __shfl_down(sq, off);
  }
  __shared__ float ss[4], ssq[4];
  if ((tid & 63) == 0) { ss[tid >> 6] = s; ssq[tid >> 6] = sq; }
  __syncthreads();
  s = ss[0] + ss[1] + ss[2] + ss[3];
  sq = ssq[0] + ssq[1] + ssq[2] + ssq[3];
  const float mean = s * (1.f / 1024.f);
  const float var = (sq - 1024.f * mean * mean) * (1.f / 1023.f);
  const float rs = rsqrtf(var + 1e-5f);
  const int c0 = tid * 4;
  ushort4 o;
  o.x = f2bf(ld_f(gamma, c0 + 0, f) * (v0 - mean) * rs + ld_f(beta, c0 + 0, f));
  o.y = f2bf(ld_f(gamma, c0 + 1, f) * (v1 - mean) * rs + ld_f(beta, c0 + 1, f));
  o.z = f2bf(ld_f(gamma, c0 + 2, f) * (v2 - mean) * rs + ld_f(beta, c0 + 2, f));
  o.w = f2bf(ld_f(gamma, c0 + 3, f) * (v3 - mean) * rs + ld_f(beta, c0 + 3, f));
  *(ushort4*)&out[row * 1024 + tid * 4] = o;
}

extern "C" void kernel_launch(void* const* d_in, const int* in_sizes, int n_in,
                              void* d_out, int out_size, void* d_ws, size_t ws_size,
                              hipStream_t stream) {
  const void* x      = d_in[0];
  const void* Wq     = d_in[1];
  const void* Wk     = d_in[2];
  const void* Wv     = d_in[3];
  const void* W1     = d_in[4];
  const void* b1     = d_in[5];
  const void* W2     = d_in[6];
  const void* b2     = d_in[7];
  const void* gamma1 = d_in[8];
  const void* beta1  = d_in[9];
  const void* gamma2 = d_in[10];
  const void* beta2  = d_in[11];
  u16* ws = (u16*)d_ws;

  const size_t M4 = 4194304;
  u16* h   = ws;
  u16* Qb  = ws + 1 * M4;
  u16* Kb  = ws + 2 * M4;
  u16* Vtb = ws + 3 * M4;
  u16* WTq = ws + 4 * M4;
  u16* x2  = ws + 4 * M4;
  u16* h2  = ws + 5 * M4;
  u16* W1T = ws + 6 * M4;
  u16* W2T = ws + 7 * M4;
  u16* ff1 = ws;
  int* flag = (int*)(ws + 8 * M4 + 9216);

  sniff_kernel<<<1, 256, 0, stream>>>((const u16*)x, flag);
  prep_kernel<<<2816, 256, 0, stream>>>(Wq, Wk, Wv, W1, W2, WTq, W1T, W2T, flag);
  ln_kernel<<<4096, 256, 0, stream>>>(x, gamma1, beta1, h, flag, 1);
  // 256x128 tiles, 8 waves: 384 blocks (n-tiles 24 -> sxp 3)
  gemm_bt<0, 4, 2, false><<<384, 512, 0, stream>>>(h, WTq, 1024, 24, 3072,
                                                   nullptr, nullptr, nullptr,
                                                   Qb, Kb, Vtb, flag);
  attn_mfma<<<1024, 256, 0, stream>>>(Qb, Kb, Vtb, x, flag, x2);
  ln_kernel<<<4096, 256, 0, stream>>>(x2, gamma2, beta2, h2, flag, 0);
  // 256x128 tiles, 8 waves: 512 blocks (n-tiles 32 -> sxp 4)
  gemm_bt<1, 4, 2, false><<<512, 512, 0, stream>>>(h2, W1T, 1024, 32, 4096,
                                                   b1, nullptr, ff1,
                                                   nullptr, nullptr, nullptr, flag);
  // FFN2: in-block split-K, 512 blocks x 4 waves
  gemm_sk<<<512, 256, 0, stream>>>(ff1, W2T, b2, x2, d_out, flag);
}